// Round 12
// baseline (111.891 us; speedup 1.0000x reference)
//
#include <hip/hip_runtime.h>
#include <hip/hip_bf16.h>

namespace {

constexpr float EPS_GN = 1e-6f;
constexpr float EPS_L2 = 1e-12f;

typedef __attribute__((ext_vector_type(8))) short bf16x8;
typedef __attribute__((ext_vector_type(4))) float f32x4;

__device__ __forceinline__ unsigned short f2bf(float f) {
  union { __hip_bfloat16 h; unsigned short u; } cv;
  cv.h = __float2bfloat16(f);
  return cv.u;
}
__device__ __forceinline__ float blo(unsigned u) { return __uint_as_float(u << 16); }
__device__ __forceinline__ float bhi(unsigned u) { return __uint_as_float(u & 0xffff0000u); }

// ---------------- prep: x->xbf/xT/sxpart AND weight conversions (r9-verified) ----------------
__global__ __launch_bounds__(256) void prep_k(const float* __restrict__ x,
                                              const float* __restrict__ qkv_w,
                                              const float* __restrict__ proj_w,
                                              unsigned short* __restrict__ xbf,
                                              unsigned short* __restrict__ xT,
                                              float* __restrict__ sxpart,
                                              unsigned short* __restrict__ qkvw_bf,
                                              unsigned short* __restrict__ pw_bf,
                                              unsigned short* __restrict__ wvt_bf) {
  __shared__ char shm[16640];
  const int bid = blockIdx.x, t = threadIdx.x;
  if (bid < 2048) {
    unsigned short (*tl)[68] = (unsigned short (*)[68])shm;
    const int b = bid >> 8, cy = (bid >> 6) & 3, nx = bid & 63;
    const int c0 = cy * 64, n0 = nx * 64;
    const int cl = t >> 2, ns = (t & 3) * 16;
    const float* xp = x + ((size_t)b << 20) + (size_t)(c0 + cl) * 4096 + n0 + ns;
    unsigned pk[8];
    float s = 0.f;
#pragma unroll
    for (int q = 0; q < 4; ++q) {
      float4 v = *(const float4*)(xp + q * 4);
      s += v.x + v.y + v.z + v.w;
      pk[2 * q + 0] = f2bf(v.x) | ((unsigned)f2bf(v.y) << 16);
      pk[2 * q + 1] = f2bf(v.z) | ((unsigned)f2bf(v.w) << 16);
    }
    unsigned short* xo = xbf + ((size_t)b << 20) + (size_t)(c0 + cl) * 4096 + n0 + ns;
    *(int4*)xo = make_int4((int)pk[0], (int)pk[1], (int)pk[2], (int)pk[3]);
    *(int4*)(xo + 8) = make_int4((int)pk[4], (int)pk[5], (int)pk[6], (int)pk[7]);
#pragma unroll
    for (int q = 0; q < 8; ++q)
      *(unsigned*)(&tl[cl][ns + 2 * q]) = pk[q];
    s += __shfl_xor(s, 1);
    s += __shfl_xor(s, 2);
    if ((t & 3) == 0)
      sxpart[((size_t)((b * 4 + cy) * 64 + cl)) * 64 + nx] = s;
    __syncthreads();
    const int nl = t >> 2, cs2 = (t & 3) * 16;
    unsigned pk2[8];
#pragma unroll
    for (int q = 0; q < 8; ++q)
      pk2[q] = (unsigned)(unsigned short)tl[cs2 + 2 * q][nl] |
               ((unsigned)(unsigned short)tl[cs2 + 2 * q + 1][nl] << 16);
    unsigned short* to = xT + ((size_t)((b << 12) + n0 + nl)) * 256 + c0 + cs2;
    *(int4*)to = make_int4((int)pk2[0], (int)pk2[1], (int)pk2[2], (int)pk2[3]);
    *(int4*)(to + 8) = make_int4((int)pk2[4], (int)pk2[5], (int)pk2[6], (int)pk2[7]);
    return;
  }
  const int cb = bid - 2048;
  if (cb < 256) {
    const float* src = (cb < 192) ? qkv_w : proj_w;
    unsigned short* dst = (cb < 192) ? qkvw_bf : pw_bf;
    int i = (cb < 192 ? cb : cb - 192) * 256 + t;
    float4 v = ((const float4*)src)[i];
    unsigned p0 = f2bf(v.x) | ((unsigned)f2bf(v.y) << 16);
    unsigned p1 = f2bf(v.z) | ((unsigned)f2bf(v.w) << 16);
    ((int2*)dst)[i] = make_int2((int)p0, (int)p1);
    return;
  }
  float (*tlf)[65] = (float (*)[65])shm;
  const int tb = cb - 256;
  const int j0 = (tb >> 2) * 64, d0 = (tb & 3) * 64;
  const float* src = qkv_w + 512 * 256;
  const int jr = t >> 2, ds = (t & 3) * 16;
#pragma unroll
  for (int q = 0; q < 4; ++q) {
    float4 v = *(const float4*)(src + (size_t)(j0 + jr) * 256 + d0 + ds + q * 4);
    tlf[jr][ds + q * 4 + 0] = v.x; tlf[jr][ds + q * 4 + 1] = v.y;
    tlf[jr][ds + q * 4 + 2] = v.z; tlf[jr][ds + q * 4 + 3] = v.w;
  }
  __syncthreads();
  const int dr = t >> 2, js = (t & 3) * 16;
  unsigned pk[8];
#pragma unroll
  for (int q = 0; q < 8; ++q)
    pk[q] = f2bf(tlf[js + 2 * q][dr]) | ((unsigned)f2bf(tlf[js + 2 * q + 1][dr]) << 16);
  unsigned short* dp = wvt_bf + (size_t)(d0 + dr) * 256 + j0 + js;
  *(int4*)dp = make_int4((int)pk[0], (int)pk[1], (int)pk[2], (int)pk[3]);
  *(int4*)(dp + 8) = make_int4((int)pk[4], (int)pk[5], (int)pk[6], (int)pk[7]);
}

// ---------------- 64x64-tile NT-GEMM macro body (verified r4-r11) ----------------
#define NT64_BODY(APTR, ALDA, BPTR, BLDB, KSTEPS)                                   \
  const int tid = threadIdx.x;                                                      \
  const int l = tid & 63, w = tid >> 6;                                             \
  const int wm = w >> 1, wn = w & 1;                                                \
  const int r = tid >> 2;                                                           \
  const unsigned short* aG = (APTR) + (size_t)(m0 + r) * (ALDA) + (tid & 3) * 16;   \
  const unsigned short* bG = (BPTR) + (size_t)(n0 + r) * (BLDB) + (tid & 3) * 16;   \
  const int g0 = (tid & 3) * 2;                                                     \
  const int w0 = r * 128 + (((g0)     ^ (r & 7)) << 4);                             \
  const int w1 = r * 128 + (((g0 + 1) ^ (r & 7)) << 4);                             \
  int rdA[2], rdB[2];                                                               \
  _Pragma("unroll")                                                                 \
  for (int i = 0; i < 2; ++i) {                                                     \
    int rm = wm * 32 + i * 16 + (l & 15);                                           \
    rdA[i] = rm * 128 + (((l >> 4) ^ (rm & 7)) << 4);                               \
    int rn = wn * 32 + i * 16 + (l & 15);                                           \
    rdB[i] = rn * 128 + (((l >> 4) ^ (rn & 7)) << 4);                               \
  }                                                                                 \
  f32x4 zero = {0.f, 0.f, 0.f, 0.f};                                                \
  f32x4 acc[2][2] = {{zero, zero}, {zero, zero}};                                   \
  for (int ks = 0; ks < (KSTEPS); ++ks) {                                           \
    int4 a0 = *(const int4*)aG, a1 = *(const int4*)(aG + 8);                        \
    int4 b0 = *(const int4*)bG, b1 = *(const int4*)(bG + 8);                        \
    aG += 64; bG += 64;                                                             \
    __syncthreads();                                                                \
    *(int4*)((char*)As + w0) = a0; *(int4*)((char*)As + w1) = a1;                   \
    *(int4*)((char*)Bs + w0) = b0; *(int4*)((char*)Bs + w1) = b1;                   \
    __syncthreads();                                                                \
    _Pragma("unroll")                                                               \
    for (int kk = 0; kk < 2; ++kk) {                                                \
      bf16x8 af[2], bf_[2];                                                         \
      _Pragma("unroll")                                                             \
      for (int i = 0; i < 2; ++i) {                                                 \
        af[i]  = *(const bf16x8*)((const char*)As + (rdA[i] ^ (kk << 6)));          \
        bf_[i] = *(const bf16x8*)((const char*)Bs + (rdB[i] ^ (kk << 6)));          \
      }                                                                             \
      _Pragma("unroll")                                                             \
      for (int i = 0; i < 2; ++i)                                                   \
        _Pragma("unroll")                                                           \
        for (int j = 0; j < 2; ++j)                                                 \
          acc[i][j] = __builtin_amdgcn_mfma_f32_16x16x32_bf16(af[i], bf_[j],        \
                                                              acc[i][j], 0, 0, 0); \
    }                                                                               \
  }                                                                                 \
  const int mB = m0 + wm * 32 + ((l >> 4) << 2);                                    \
  const int nB = n0 + wn * 32 + (l & 15);

// ---------------- Sxx = X X^T, split-K 8: grid (4,4,64) (r9-verified) ----------------
__global__ __launch_bounds__(256) void sxx64_k(const unsigned short* __restrict__ xbf,
                                               float* __restrict__ part) {
  __shared__ unsigned short As[4096];
  __shared__ unsigned short Bs[4096];
  const int z = blockIdx.z;
  const int b = z >> 3, sl = z & 7;
  const int m0 = blockIdx.y << 6, n0 = blockIdx.x << 6;
  const unsigned short* base = xbf + ((size_t)b << 20) + (size_t)sl * 512;
  NT64_BODY(base, 4096, base, 4096, 8)
  float* po = part + ((size_t)z << 16);
#pragma unroll
  for (int i = 0; i < 2; ++i)
#pragma unroll
    for (int rr = 0; rr < 4; ++rr)
#pragma unroll
      for (int j = 0; j < 2; ++j)
        po[(size_t)(mB + i * 16 + rr) * 256 + nB + j * 16] = acc[i][j][rr];
}

// ---------------- out = F~ @ X + h~: grid (64,4,8) (r9-verified) ----------------
__global__ __launch_bounds__(256) void out64_k(const unsigned short* __restrict__ Fbf,
                                               const unsigned short* __restrict__ xT,
                                               const float* __restrict__ hvec,
                                               float* __restrict__ outF) {
  __shared__ unsigned short As[4096];
  __shared__ unsigned short Bs[4096];
  const int b = blockIdx.z;
  const int m0 = blockIdx.y << 6, n0 = blockIdx.x << 6;
  NT64_BODY(Fbf + ((size_t)b << 16), 256, xT + ((size_t)b << 20), 256, 4)
#pragma unroll
  for (int i = 0; i < 2; ++i) {
#pragma unroll
    for (int rr = 0; rr < 4; ++rr) {
      int mi = mB + i * 16 + rr;
      float hv = hvec[b * 256 + mi];
      size_t rowo = ((size_t)b << 20) + (size_t)mi * 4096;
#pragma unroll
      for (int j = 0; j < 2; ++j)
        outF[rowo + nB + j * 16] = acc[i][j][rr] + hv;
    }
  }
}

// ---------------- gfill2: per-block GN stats + G tile + wsv slice + hvec zero ----------------
__global__ __launch_bounds__(256) void gfill2_k(const float* __restrict__ part,
                                                const float* __restrict__ sxpart,
                                                const float* __restrict__ gamma,
                                                const float* __restrict__ beta,
                                                const unsigned short* __restrict__ qkvw_bf,
                                                float* __restrict__ avec,
                                                float* __restrict__ evec,
                                                float* __restrict__ wsv,
                                                float* __restrict__ hvec,
                                                unsigned short* __restrict__ Gbf) {
  __shared__ float sav[256], sev[256], ssx[256], ssv[256];
  const int b = blockIdx.y, t = threadIdx.x;

  // phase A: GN stats for channel c = t
  {
    const float* sp = sxpart + ((size_t)(b * 256 + t) << 6);
    float sxv = 0.f;
#pragma unroll 4
    for (int i = 0; i < 64; ++i) sxv += sp[i];
    float dg = 0.f;
#pragma unroll
    for (int s = 0; s < 8; ++s) dg += part[((size_t)(b * 8 + s) << 16) + t * 257];
    float gs = sxv, g2 = dg;
#pragma unroll
    for (int off = 1; off < 16; off <<= 1) {
      gs += __shfl_xor(gs, off);
      g2 += __shfl_xor(g2, off);
    }
    const float inv = 1.f / 65536.f;
    float mu = gs * inv;
    float var = g2 * inv - mu * mu;
    float rstd = rsqrtf(var + EPS_GN);
    float av = gamma[t] * rstd;
    float ev = beta[t] - mu * av;
    sav[t] = av; sev[t] = ev; ssx[t] = sxv;
    ssv[t] = av * sxv + 4096.f * ev;
    if (blockIdx.x == 0) {
      avec[b * 256 + t] = av;
      evec[b * 256 + t] = ev;
      hvec[b * 256 + t] = 0.f;   // zero for fgen2's atomics
    }
  }
  __syncthreads();

  // phase B: wsv slice (32 rows per block, 8 threads per row)
  {
    const int row = blockIdx.x * 32 + (t >> 3);
    const int seg = (t & 7) * 32;
    const unsigned short* wr = qkvw_bf + (size_t)row * 256 + seg;
    float acc = 0.f;
#pragma unroll
    for (int d = 0; d < 32; d += 8) {
      int4 v = *(const int4*)(wr + d);
      acc += blo((unsigned)v.x) * ssv[seg + d + 0] + bhi((unsigned)v.x) * ssv[seg + d + 1];
      acc += blo((unsigned)v.y) * ssv[seg + d + 2] + bhi((unsigned)v.y) * ssv[seg + d + 3];
      acc += blo((unsigned)v.z) * ssv[seg + d + 4] + bhi((unsigned)v.z) * ssv[seg + d + 5];
      acc += blo((unsigned)v.w) * ssv[seg + d + 6] + bhi((unsigned)v.w) * ssv[seg + d + 7];
    }
    acc += __shfl_xor(acc, 1);
    acc += __shfl_xor(acc, 2);
    acc += __shfl_xor(acc, 4);
    if ((t & 7) == 0) wsv[b * 512 + row] = acc;
  }

  // phase C: G tile
  {
    const int rr_ = blockIdx.x * 16 + (t >> 4);
    const int cs = (t & 15) * 16;
    const float ac = sav[rr_], ec = sev[rr_], sxc = ssx[rr_];
    unsigned pk[8];
#pragma unroll
    for (int q = 0; q < 8; ++q) {
      unsigned lohi[2];
#pragma unroll
      for (int h = 0; h < 2; ++h) {
        int d = cs + 2 * q + h;
        float S = 0.f;
#pragma unroll
        for (int s = 0; s < 8; ++s)
          S += part[(((size_t)(b * 8 + s)) << 16) + (size_t)rr_ * 256 + d];
        float gv = ac * sav[d] * S + ac * sev[d] * sxc + ec * sav[d] * ssx[d] +
                   4096.f * ec * sev[d];
        lohi[h] = f2bf(gv);
      }
      pk[q] = lohi[0] | (lohi[1] << 16);
    }
    unsigned short* gp = Gbf + ((size_t)b << 16) + (size_t)rr_ * 256 + cs;
    *(int4*)gp = make_int4((int)pk[0], (int)pk[1], (int)pk[2], (int)pk[3]);
    *(int4*)(gp + 8) = make_int4((int)pk[4], (int)pk[5], (int)pk[6], (int)pk[7]);
  }
}

// ---------------- U = [Wq;Wk] @ G  (bf16 out) ----------------
__global__ __launch_bounds__(256) void ugemm_k(const unsigned short* __restrict__ qkvw,
                                               const unsigned short* __restrict__ Gbf,
                                               unsigned short* __restrict__ Ubf) {
  __shared__ unsigned short As[4096];
  __shared__ unsigned short Bs[4096];
  const int b = blockIdx.z;
  const int m0 = blockIdx.y << 6, n0 = blockIdx.x << 6;
  NT64_BODY(qkvw, 256, Gbf + ((size_t)b << 16), 256, 4)
  unsigned short* pu = Ubf + ((size_t)b << 17);
#pragma unroll
  for (int i = 0; i < 2; ++i)
#pragma unroll
    for (int rr = 0; rr < 4; ++rr)
#pragma unroll
      for (int j = 0; j < 2; ++j)
        pu[(size_t)(mB + i * 16 + rr) * 256 + nB + j * 16] = f2bf(acc[i][j][rr]);
}

// ---------------- fgen2: Y1 slice in LDS, then F tile + epilogue ----------------
// grid (4 d-tiles, 4 t-tiles, 8 b). Replaces r11's y1h_k + fgen_k.
__global__ __launch_bounds__(256) void fgen2_k(const unsigned short* __restrict__ wvt,
                                               const unsigned short* __restrict__ Abf,
                                               const unsigned short* __restrict__ pw,
                                               const float* __restrict__ abv,
                                               const float* __restrict__ proj_w,
                                               const float* __restrict__ proj_b,
                                               const float* __restrict__ avec,
                                               const float* __restrict__ evec,
                                               unsigned short* __restrict__ Fbf,
                                               float* __restrict__ hvec) {
  __shared__ unsigned short As[4096];
  __shared__ unsigned short Bs[4096];
  __shared__ unsigned short Ylds[16384];  // 4 ks-buffers, Bs-swizzled layout
  const int b = blockIdx.z;
  const int d0 = blockIdx.x << 6;   // F col tile == Y1 row tile
  const int t0 = blockIdx.y << 6;   // F row tile
  const int tid = threadIdx.x;
  const int l = tid & 63, w = tid >> 6;
  const int wm = w >> 1, wn = w & 1;
  const int r = tid >> 2;
  const int g0 = (tid & 3) * 2;
  const int w0 = r * 128 + ((g0 ^ (r & 7)) << 4);
  const int w1 = r * 128 + (((g0 + 1) ^ (r & 7)) << 4);
  int rdA[2], rdB[2];
#pragma unroll
  for (int i = 0; i < 2; ++i) {
    int rm = wm * 32 + i * 16 + (l & 15);
    rdA[i] = rm * 128 + (((l >> 4) ^ (rm & 7)) << 4);
    int rn = wn * 32 + i * 16 + (l & 15);
    rdB[i] = rn * 128 + (((l >> 4) ^ (rn & 7)) << 4);
  }
  const int mloc = wm * 32 + ((l >> 4) << 2);
  const int nloc = wn * 32 + (l & 15);
  f32x4 zero = {0.f, 0.f, 0.f, 0.f};

  // ---- step 1: Y1[d0+dl][i] = sum_j wvt[d][j] A[i][j], i in 4 tiles of 64 ----
  for (int ni = 0; ni < 4; ++ni) {
    const unsigned short* aG = wvt + (size_t)(d0 + r) * 256 + (tid & 3) * 16;
    const unsigned short* bG = Abf + ((size_t)b << 16) + (size_t)(ni * 64 + r) * 256 + (tid & 3) * 16;
    f32x4 acc[2][2] = {{zero, zero}, {zero, zero}};
    for (int ks = 0; ks < 4; ++ks) {
      int4 a0 = *(const int4*)aG, a1 = *(const int4*)(aG + 8);
      int4 b0 = *(const int4*)bG, b1 = *(const int4*)(bG + 8);
      aG += 64; bG += 64;
      __syncthreads();
      *(int4*)((char*)As + w0) = a0; *(int4*)((char*)As + w1) = a1;
      *(int4*)((char*)Bs + w0) = b0; *(int4*)((char*)Bs + w1) = b1;
      __syncthreads();
#pragma unroll
      for (int kk = 0; kk < 2; ++kk) {
        bf16x8 af[2], bf_[2];
#pragma unroll
        for (int i = 0; i < 2; ++i) {
          af[i]  = *(const bf16x8*)((const char*)As + (rdA[i] ^ (kk << 6)));
          bf_[i] = *(const bf16x8*)((const char*)Bs + (rdB[i] ^ (kk << 6)));
        }
#pragma unroll
        for (int i = 0; i < 2; ++i)
#pragma unroll
          for (int j = 0; j < 2; ++j)
            acc[i][j] = __builtin_amdgcn_mfma_f32_16x16x32_bf16(af[i], bf_[j], acc[i][j], 0, 0, 0);
      }
    }
    // write tile to Ylds in Bs-swizzled layout (ks-buffer = ni)
#pragma unroll
    for (int i = 0; i < 2; ++i) {
#pragma unroll
      for (int rr = 0; rr < 4; ++rr) {
        int dl = mloc + i * 16 + rr;
#pragma unroll
        for (int j = 0; j < 2; ++j) {
          int kl = nloc + j * 16;  // k-local within this ks-buffer (0..63)
          int byte = ni * 8192 + dl * 128 + (((kl >> 3) ^ (dl & 7)) << 4) + (kl & 7) * 2;
          *(unsigned short*)((char*)Ylds + byte) = f2bf(acc[i][j][rr]);
        }
      }
    }
  }
  __syncthreads();

  // ---- step 2: F[t0..][d0..] = sum_i pw[t][i] * Ylds[d][i] ----
  f32x4 acc2[2][2] = {{zero, zero}, {zero, zero}};
  {
    const unsigned short* aG = pw + (size_t)(t0 + r) * 256 + (tid & 3) * 16;
    for (int ks = 0; ks < 4; ++ks) {
      int4 a0 = *(const int4*)aG, a1 = *(const int4*)(aG + 8);
      aG += 64;
      __syncthreads();
      *(int4*)((char*)As + w0) = a0; *(int4*)((char*)As + w1) = a1;
      __syncthreads();
#pragma unroll
      for (int kk = 0; kk < 2; ++kk) {
        bf16x8 af[2], bf_[2];
#pragma unroll
        for (int i = 0; i < 2; ++i) {
          af[i]  = *(const bf16x8*)((const char*)As + (rdA[i] ^ (kk << 6)));
          bf_[i] = *(const bf16x8*)((const char*)Ylds + ks * 8192 + (rdB[i] ^ (kk << 6)));
        }
#pragma unroll
        for (int i = 0; i < 2; ++i)
#pragma unroll
          for (int j = 0; j < 2; ++j)
            acc2[i][j] = __builtin_amdgcn_mfma_f32_16x16x32_bf16(af[i], bf_[j], acc2[i][j], 0, 0, 0);
      }
    }
  }

  // ---- epilogue: Fbf = F*diag(a)+I, hvec += F e (+ base on d0==0) ----
  float* hred = (float*)Bs;                 // Bs free after step 1
  float* abl  = (float*)((char*)Bs + 1024);
  if (tid < 64) hred[tid] = 0.f;
  if (d0 == 0) abl[tid] = abv[b * 256 + tid];
  __syncthreads();
#pragma unroll
  for (int i = 0; i < 2; ++i) {
#pragma unroll
    for (int rr = 0; rr < 4; ++rr) {
      int tl_ = mloc + i * 16 + rr;
      int t = t0 + tl_;
      float hp = 0.f;
#pragma unroll
      for (int j = 0; j < 2; ++j) {
        int d = d0 + nloc + j * 16;
        float f = acc2[i][j][rr];
        float fa = f * avec[b * 256 + d] + (t == d ? 1.f : 0.f);
        Fbf[((size_t)b << 16) + (size_t)t * 256 + d] = f2bf(fa);
        hp += f * evec[b * 256 + d];
      }
      atomicAdd(&hred[tl_], hp);
    }
  }
  __syncthreads();
  if (tid < 64) atomicAdd(&hvec[b * 256 + t0 + tid], hred[tid]);
  if (d0 == 0) {
    const int t = t0 + (tid >> 2);
    const int qd = (tid & 3) * 64;
    const float* pr = proj_w + (size_t)t * 256 + qd;
    float s = 0.f;
#pragma unroll 8
    for (int i = 0; i < 64; ++i) s += pr[i] * abl[qd + i];
    s += __shfl_xor(s, 1);
    s += __shfl_xor(s, 2);
    if ((tid & 3) == 0) atomicAdd(&hvec[b * 256 + t], proj_b[t] + s);
  }
}

// ---------------- fused logits GEMM + inline norms + softmax + A.bv (r9-verified) ----------------
__global__ __launch_bounds__(256) void logsm_k(
    const unsigned short* __restrict__ Ubf,   // [b][512][256]
    const unsigned short* __restrict__ qkvw,  // Wq rows at 0, Wk rows at +65536
    const float* __restrict__ wsv,
    const float* __restrict__ qkv_b, const float* __restrict__ temp,
    unsigned short* __restrict__ Abf, float* __restrict__ abv) {
  __shared__ unsigned short As[64 * 64];    // 8KB
  __shared__ unsigned short Bs[256 * 64];   // 32KB
  const int b = blockIdx.y, m0 = blockIdx.x * 64;
  const int tid = threadIdx.x;
  const int l = tid & 63, w = tid >> 6;
  const unsigned short* wk = qkvw + 65536;

  const int ar = tid >> 2, ac = tid & 3;
  const unsigned short* aG = Ubf + ((size_t)b << 17) + (size_t)(m0 + ar) * 256 + ac * 16;
  const unsigned short* bG = wk + (size_t)tid * 256;
  const int g0 = ac * 2;
  const int wA0 = ar * 128 + (((g0)     ^ (ar & 7)) << 4);
  const int wA1 = ar * 128 + (((g0 + 1) ^ (ar & 7)) << 4);
  int wBoff[8];
#pragma unroll
  for (int c = 0; c < 8; ++c) wBoff[c] = tid * 128 + ((c ^ (tid & 7)) << 4);

  int rdA;
  { int rm = w * 16 + (l & 15); rdA = rm * 128 + (((l >> 4) ^ (rm & 7)) << 4); }
  int rdB[16];
#pragma unroll
  for (int nf = 0; nf < 16; ++nf) {
    int rn = nf * 16 + (l & 15);
    rdB[nf] = rn * 128 + (((l >> 4) ^ (rn & 7)) << 4);
  }

  f32x4 zero = {0.f, 0.f, 0.f, 0.f};
  f32x4 acc[16];
#pragma unroll
  for (int nf = 0; nf < 16; ++nf) acc[nf] = zero;

  for (int ks = 0; ks < 4; ++ks) {
    int4 a0 = *(const int4*)aG;
    int4 a1 = *(const int4*)(aG + 8);
    int4 bv[8];
#pragma unroll
    for (int c = 0; c < 8; ++c) bv[c] = *(const int4*)(bG + c * 8);
    aG += 64; bG += 64;
    __syncthreads();
    *(int4*)((char*)As + wA0) = a0;
    *(int4*)((char*)As + wA1) = a1;
#pragma unroll
    for (int c = 0; c < 8; ++c) *(int4*)((char*)Bs + wBoff[c]) = bv[c];
    __syncthreads();
#pragma unroll
    for (int kk = 0; kk < 2; ++kk) {
      bf16x8 af = *(const bf16x8*)((const char*)As + (rdA ^ (kk << 6)));
#pragma unroll
      for (int nf = 0; nf < 16; ++nf) {
        bf16x8 bf_ = *(const bf16x8*)((const char*)Bs + (rdB[nf] ^ (kk << 6)));
        acc[nf] = __builtin_amdgcn_mfma_f32_16x16x32_bf16(af, bf_, acc[nf], 0, 0, 0);
      }
    }
  }

  __syncthreads();
  float* sKs  = (float*)As;
  float* sWks = sKs + 256;
  float* sBk  = sWks + 256;
  float* sBv  = sBk + 256;
  float* sQs  = sBv + 256;
  {
    const unsigned short* ur = Ubf + ((size_t)b << 17) + (size_t)(256 + tid) * 256;
    const unsigned short* wr = wk + (size_t)tid * 256;
    float dot = 0.f;
    for (int dd = 0; dd < 256; dd += 8) {
      int4 uv = *(const int4*)(ur + dd);
      int4 wv = *(const int4*)(wr + dd);
      dot += blo((unsigned)uv.x) * blo((unsigned)wv.x) + bhi((unsigned)uv.x) * bhi((unsigned)wv.x);
      dot += blo((unsigned)uv.y) * blo((unsigned)wv.y) + bhi((unsigned)uv.y) * bhi((unsigned)wv.y);
      dot += blo((unsigned)uv.z) * blo((unsigned)wv.z) + bhi((unsigned)uv.z) * bhi((unsigned)wv.z);
      dot += blo((unsigned)uv.w) * blo((unsigned)wv.w) + bhi((unsigned)uv.w) * bhi((unsigned)wv.w);
    }
    float bk = qkv_b[256 + tid];
    float wks = wsv[b * 512 + 256 + tid];
    float n2 = dot + 2.f * bk * wks + 4096.f * bk * bk;
    sKs[tid]  = 1.f / fmaxf(sqrtf(fmaxf(n2, 0.f)), EPS_L2);
    sWks[tid] = wks;
    sBk[tid]  = bk;
    sBv[tid]  = qkv_b[512 + tid];
  }
  if (tid < 64) {
    int m = m0 + tid;
    const unsigned short* ur = Ubf + ((size_t)b << 17) + (size_t)m * 256;
    const unsigned short* wr = qkvw + (size_t)m * 256;
    float dot = 0.f;
    for (int dd = 0; dd < 256; dd += 8) {
      int4 uv = *(const int4*)(ur + dd);
      int4 wv = *(const int4*)(wr + dd);
      dot += blo((unsigned)uv.x) * blo((unsigned)wv.x) + bhi((unsigned)uv.x) * bhi((unsigned)wv.x);
      dot += blo((unsigned)uv.y) * blo((unsigned)wv.y) + bhi((unsigned)uv.y) * bhi((unsigned)wv.y);
      dot += blo((unsigned)uv.z) * blo((unsigned)wv.z) + bhi((unsigned)uv.z) * bhi((unsigned)wv.z);
      dot += blo((unsigned)uv.w) * blo((unsigned)wv.w) + bhi((unsigned)uv.w) * bhi((unsigned)wv.w);
    }
    float bq = qkv_b[m], wqs = wsv[b * 512 + m];
    float n2 = dot + 2.f * bq * wqs + 4096.f * bq * bq;
    sQs[tid] = 1.f / fmaxf(sqrtf(fmaxf(n2, 0.f)), EPS_L2);
  }
  __syncthreads();

  const float T = temp[0];
  const int lrow = w * 16 + ((l >> 4) << 2);
  const int mrow = m0 + lrow;
  float ks_c[16], wks_c[16], bk_c[16], bv_c[16];
#pragma unroll
  for (int nf = 0; nf < 16; ++nf) {
    int n = nf * 16 + (l & 15);
    ks_c[nf] = sKs[n]; wks_c[nf] = sWks[n]; bk_c[nf] = sBk[n]; bv_c[nf] = sBv[n];
  }
#pragma unroll
  for (int rr = 0; rr < 4; ++rr) {
    int m = mrow + rr;
    float qs = sQs[lrow + rr], wqs = wsv[b * 512 + m], bq = qkv_b[m];
    float sc = T * qs;
#pragma unroll
    for (int nf = 0; nf < 16; ++nf)
      acc[nf][rr] = sc * ks_c[nf] *
                    (acc[nf][rr] + bq * wks_c[nf] + bk_c[nf] * wqs + 4096.f * bq * bk_c[nf]);
    float mx = acc[0][rr];
#pragma unroll
    for (int nf = 1; nf < 16; ++nf) mx = fmaxf(mx, acc[nf][rr]);
    mx = fmaxf(mx, __shfl_xor(mx, 1));
    mx = fmaxf(mx, __shfl_xor(mx, 2));
    mx = fmaxf(mx, __shfl_xor(mx, 4));
    mx = fmaxf(mx, __shfl_xor(mx, 8));
    float s = 0.f, ab = 0.f;
#pragma unroll
    for (int nf = 0; nf < 16; ++nf) {
      float e = __expf(acc[nf][rr] - mx);
      acc[nf][rr] = e;
      s += e; ab += e * bv_c[nf];
    }
#pragma unroll
    for (int off = 1; off < 16; off <<= 1) {
      s += __shfl_xor(s, off);
      ab += __shfl_xor(ab, off);
    }
    float inv = 1.f / s;
    unsigned short* arow = Abf + ((size_t)b << 16) + (size_t)m * 256 + (l & 15);
#pragma unroll
    for (int nf = 0; nf < 16; ++nf)
      arow[nf * 16] = f2bf(acc[nf][rr] * inv);
    if ((l & 15) == 0) abv[b * 256 + m] = ab * inv;
  }
}

}  // namespace

extern "C" void kernel_launch(void* const* d_in, const int* in_sizes, int n_in,
                              void* d_out, int out_size, void* d_ws, size_t ws_size,
                              hipStream_t stream) {
  const float* x      = (const float*)d_in[0];
  const float* gamma  = (const float*)d_in[1];
  const float* beta   = (const float*)d_in[2];
  const float* qkv_w  = (const float*)d_in[3];
  const float* qkv_b  = (const float*)d_in[4];
  const float* temp   = (const float*)d_in[5];
  const float* proj_w = (const float*)d_in[6];
  const float* proj_b = (const float*)d_in[7];
  float* out = (float*)d_out;

  char* ws = (char*)d_ws;
  const size_t MB = 1048576;
  unsigned short* qkvw_bf = (unsigned short*)(ws);             // 384KB
  unsigned short* pw_bf   = (unsigned short*)(ws + 0x60000);   // 128KB
  unsigned short* wvt_bf  = (unsigned short*)(ws + 0x80000);   // 128KB
  float* avec  = (float*)(ws + 0xA0000);
  float* evec  = (float*)(ws + 0xA2000);
  float* wsv   = (float*)(ws + 0xA6000);
  float* hvec  = (float*)(ws + 0xAA000);
  float* abv   = (float*)(ws + 0xAC000);
  float* sxpart = (float*)(ws + 1 * MB);                   // 512KB
  float* part   = (float*)(ws + 2 * MB);                   // 16MB
  unsigned short* Gbf = (unsigned short*)(ws + 18 * MB);   // 1MB
  unsigned short* Ubf = (unsigned short*)(ws + 19 * MB);   // 2MB
  unsigned short* Abf = (unsigned short*)(ws + 21 * MB);   // 1MB
  unsigned short* Fbf = (unsigned short*)(ws + 23 * MB);   // 1MB
  unsigned short* xbf = (unsigned short*)(ws + 24 * MB);   // 16MB
  unsigned short* xT  = (unsigned short*)(ws + 40 * MB);   // 16MB
  if (ws_size < 56 * MB) return;

  // 1. x prep + weight conversions
  prep_k<<<2320, 256, 0, stream>>>(x, qkv_w, proj_w, xbf, xT, sxpart,
                                   qkvw_bf, pw_bf, wvt_bf);

  // 2. Sxx = X X^T (64^2 tiles, split-K 8 -> 1024 blocks, 4/CU)
  sxx64_k<<<dim3(4, 4, 64), 256, 0, stream>>>(xbf, part);

  // 3. gfill2: stats + G + wsv + hvec zero
  gfill2_k<<<dim3(16, 8), 256, 0, stream>>>(part, sxpart, gamma, beta, qkvw_bf,
                                            avec, evec, wsv, hvec, Gbf);

  // 4. U = [Wq;Wk] @ G
  ugemm_k<<<dim3(4, 8, 8), 256, 0, stream>>>(qkvw_bf, Gbf, Ubf);

  // 5. logits + inline norms + softmax + A.bv
  logsm_k<<<dim3(4, 8), 256, 0, stream>>>(Ubf, qkvw_bf, wsv, qkv_b, temp, Abf, abv);

  // 6. fgen2: Y1-in-LDS + F + Fbf(=F diag(a)+I) + hvec (replaces y1h+fgen)
  fgen2_k<<<dim3(4, 4, 8), 256, 0, stream>>>(wvt_bf, Abf, pw_bf, abv, proj_w, proj_b,
                                             avec, evec, Fbf, hvec);

  // 7. out = F~ @ X + h~ (2048 blocks, 8/CU)
  out64_k<<<dim3(64, 4, 8), 256, 0, stream>>>(Fbf, xT, hvec, out);
}

// Round 13
// 110.131 us; speedup vs baseline: 1.0160x; 1.0160x over previous
//
#include <hip/hip_runtime.h>
#include <hip/hip_bf16.h>

namespace {

constexpr float EPS_GN = 1e-6f;
constexpr float EPS_L2 = 1e-12f;

typedef __attribute__((ext_vector_type(8))) short bf16x8;
typedef __attribute__((ext_vector_type(4))) float f32x4;

__device__ __forceinline__ unsigned short f2bf(float f) {
  union { __hip_bfloat16 h; unsigned short u; } cv;
  cv.h = __float2bfloat16(f);
  return cv.u;
}
__device__ __forceinline__ float blo(unsigned u) { return __uint_as_float(u << 16); }
__device__ __forceinline__ float bhi(unsigned u) { return __uint_as_float(u & 0xffff0000u); }

// ---------------- prep: x->xbf/xT/sxpart AND weight conversions (r9-verified) ----------------
__global__ __launch_bounds__(256) void prep_k(const float* __restrict__ x,
                                              const float* __restrict__ qkv_w,
                                              const float* __restrict__ proj_w,
                                              unsigned short* __restrict__ xbf,
                                              unsigned short* __restrict__ xT,
                                              float* __restrict__ sxpart,
                                              unsigned short* __restrict__ qkvw_bf,
                                              unsigned short* __restrict__ pw_bf,
                                              unsigned short* __restrict__ wvt_bf) {
  __shared__ char shm[16640];
  const int bid = blockIdx.x, t = threadIdx.x;
  if (bid < 2048) {
    unsigned short (*tl)[68] = (unsigned short (*)[68])shm;
    const int b = bid >> 8, cy = (bid >> 6) & 3, nx = bid & 63;
    const int c0 = cy * 64, n0 = nx * 64;
    const int cl = t >> 2, ns = (t & 3) * 16;
    const float* xp = x + ((size_t)b << 20) + (size_t)(c0 + cl) * 4096 + n0 + ns;
    unsigned pk[8];
    float s = 0.f;
#pragma unroll
    for (int q = 0; q < 4; ++q) {
      float4 v = *(const float4*)(xp + q * 4);
      s += v.x + v.y + v.z + v.w;
      pk[2 * q + 0] = f2bf(v.x) | ((unsigned)f2bf(v.y) << 16);
      pk[2 * q + 1] = f2bf(v.z) | ((unsigned)f2bf(v.w) << 16);
    }
    unsigned short* xo = xbf + ((size_t)b << 20) + (size_t)(c0 + cl) * 4096 + n0 + ns;
    *(int4*)xo = make_int4((int)pk[0], (int)pk[1], (int)pk[2], (int)pk[3]);
    *(int4*)(xo + 8) = make_int4((int)pk[4], (int)pk[5], (int)pk[6], (int)pk[7]);
#pragma unroll
    for (int q = 0; q < 8; ++q)
      *(unsigned*)(&tl[cl][ns + 2 * q]) = pk[q];
    s += __shfl_xor(s, 1);
    s += __shfl_xor(s, 2);
    if ((t & 3) == 0)
      sxpart[((size_t)((b * 4 + cy) * 64 + cl)) * 64 + nx] = s;
    __syncthreads();
    const int nl = t >> 2, cs2 = (t & 3) * 16;
    unsigned pk2[8];
#pragma unroll
    for (int q = 0; q < 8; ++q)
      pk2[q] = (unsigned)(unsigned short)tl[cs2 + 2 * q][nl] |
               ((unsigned)(unsigned short)tl[cs2 + 2 * q + 1][nl] << 16);
    unsigned short* to = xT + ((size_t)((b << 12) + n0 + nl)) * 256 + c0 + cs2;
    *(int4*)to = make_int4((int)pk2[0], (int)pk2[1], (int)pk2[2], (int)pk2[3]);
    *(int4*)(to + 8) = make_int4((int)pk2[4], (int)pk2[5], (int)pk2[6], (int)pk2[7]);
    return;
  }
  const int cb = bid - 2048;
  if (cb < 256) {
    const float* src = (cb < 192) ? qkv_w : proj_w;
    unsigned short* dst = (cb < 192) ? qkvw_bf : pw_bf;
    int i = (cb < 192 ? cb : cb - 192) * 256 + t;
    float4 v = ((const float4*)src)[i];
    unsigned p0 = f2bf(v.x) | ((unsigned)f2bf(v.y) << 16);
    unsigned p1 = f2bf(v.z) | ((unsigned)f2bf(v.w) << 16);
    ((int2*)dst)[i] = make_int2((int)p0, (int)p1);
    return;
  }
  float (*tlf)[65] = (float (*)[65])shm;
  const int tb = cb - 256;
  const int j0 = (tb >> 2) * 64, d0 = (tb & 3) * 64;
  const float* src = qkv_w + 512 * 256;
  const int jr = t >> 2, ds = (t & 3) * 16;
#pragma unroll
  for (int q = 0; q < 4; ++q) {
    float4 v = *(const float4*)(src + (size_t)(j0 + jr) * 256 + d0 + ds + q * 4);
    tlf[jr][ds + q * 4 + 0] = v.x; tlf[jr][ds + q * 4 + 1] = v.y;
    tlf[jr][ds + q * 4 + 2] = v.z; tlf[jr][ds + q * 4 + 3] = v.w;
  }
  __syncthreads();
  const int dr = t >> 2, js = (t & 3) * 16;
  unsigned pk[8];
#pragma unroll
  for (int q = 0; q < 8; ++q)
    pk[q] = f2bf(tlf[js + 2 * q][dr]) | ((unsigned)f2bf(tlf[js + 2 * q + 1][dr]) << 16);
  unsigned short* dp = wvt_bf + (size_t)(d0 + dr) * 256 + j0 + js;
  *(int4*)dp = make_int4((int)pk[0], (int)pk[1], (int)pk[2], (int)pk[3]);
  *(int4*)(dp + 8) = make_int4((int)pk[4], (int)pk[5], (int)pk[6], (int)pk[7]);
}

// ---------------- 64x64-tile NT-GEMM macro body (verified r4-r11) ----------------
#define NT64_BODY(APTR, ALDA, BPTR, BLDB, KSTEPS)                                   \
  const int tid = threadIdx.x;                                                      \
  const int l = tid & 63, w = tid >> 6;                                             \
  const int wm = w >> 1, wn = w & 1;                                                \
  const int r = tid >> 2;                                                           \
  const unsigned short* aG = (APTR) + (size_t)(m0 + r) * (ALDA) + (tid & 3) * 16;   \
  const unsigned short* bG = (BPTR) + (size_t)(n0 + r) * (BLDB) + (tid & 3) * 16;   \
  const int g0 = (tid & 3) * 2;                                                     \
  const int w0 = r * 128 + (((g0)     ^ (r & 7)) << 4);                             \
  const int w1 = r * 128 + (((g0 + 1) ^ (r & 7)) << 4);                             \
  int rdA[2], rdB[2];                                                               \
  _Pragma("unroll")                                                                 \
  for (int i = 0; i < 2; ++i) {                                                     \
    int rm = wm * 32 + i * 16 + (l & 15);                                           \
    rdA[i] = rm * 128 + (((l >> 4) ^ (rm & 7)) << 4);                               \
    int rn = wn * 32 + i * 16 + (l & 15);                                           \
    rdB[i] = rn * 128 + (((l >> 4) ^ (rn & 7)) << 4);                               \
  }                                                                                 \
  f32x4 zero = {0.f, 0.f, 0.f, 0.f};                                                \
  f32x4 acc[2][2] = {{zero, zero}, {zero, zero}};                                   \
  for (int ks = 0; ks < (KSTEPS); ++ks) {                                           \
    int4 a0 = *(const int4*)aG, a1 = *(const int4*)(aG + 8);                        \
    int4 b0 = *(const int4*)bG, b1 = *(const int4*)(bG + 8);                        \
    aG += 64; bG += 64;                                                             \
    __syncthreads();                                                                \
    *(int4*)((char*)As + w0) = a0; *(int4*)((char*)As + w1) = a1;                   \
    *(int4*)((char*)Bs + w0) = b0; *(int4*)((char*)Bs + w1) = b1;                   \
    __syncthreads();                                                                \
    _Pragma("unroll")                                                               \
    for (int kk = 0; kk < 2; ++kk) {                                                \
      bf16x8 af[2], bf_[2];                                                         \
      _Pragma("unroll")                                                             \
      for (int i = 0; i < 2; ++i) {                                                 \
        af[i]  = *(const bf16x8*)((const char*)As + (rdA[i] ^ (kk << 6)));          \
        bf_[i] = *(const bf16x8*)((const char*)Bs + (rdB[i] ^ (kk << 6)));          \
      }                                                                             \
      _Pragma("unroll")                                                             \
      for (int i = 0; i < 2; ++i)                                                   \
        _Pragma("unroll")                                                           \
        for (int j = 0; j < 2; ++j)                                                 \
          acc[i][j] = __builtin_amdgcn_mfma_f32_16x16x32_bf16(af[i], bf_[j],        \
                                                              acc[i][j], 0, 0, 0); \
    }                                                                               \
  }                                                                                 \
  const int mB = m0 + wm * 32 + ((l >> 4) << 2);                                    \
  const int nB = n0 + wn * 32 + (l & 15);

// ---------------- Sxx = X X^T, split-K 8: grid (4,4,64) (r9-verified) ----------------
__global__ __launch_bounds__(256) void sxx64_k(const unsigned short* __restrict__ xbf,
                                               float* __restrict__ part) {
  __shared__ unsigned short As[4096];
  __shared__ unsigned short Bs[4096];
  const int z = blockIdx.z;
  const int b = z >> 3, sl = z & 7;
  const int m0 = blockIdx.y << 6, n0 = blockIdx.x << 6;
  const unsigned short* base = xbf + ((size_t)b << 20) + (size_t)sl * 512;
  NT64_BODY(base, 4096, base, 4096, 8)
  float* po = part + ((size_t)z << 16);
#pragma unroll
  for (int i = 0; i < 2; ++i)
#pragma unroll
    for (int rr = 0; rr < 4; ++rr)
#pragma unroll
      for (int j = 0; j < 2; ++j)
        po[(size_t)(mB + i * 16 + rr) * 256 + nB + j * 16] = acc[i][j][rr];
}

// ---------------- out = F~ @ X + h~: grid (64,4,8) (r9-verified) ----------------
__global__ __launch_bounds__(256) void out64_k(const unsigned short* __restrict__ Fbf,
                                               const unsigned short* __restrict__ xT,
                                               const float* __restrict__ hvec,
                                               float* __restrict__ outF) {
  __shared__ unsigned short As[4096];
  __shared__ unsigned short Bs[4096];
  const int b = blockIdx.z;
  const int m0 = blockIdx.y << 6, n0 = blockIdx.x << 6;
  NT64_BODY(Fbf + ((size_t)b << 16), 256, xT + ((size_t)b << 20), 256, 4)
#pragma unroll
  for (int i = 0; i < 2; ++i) {
#pragma unroll
    for (int rr = 0; rr < 4; ++rr) {
      int mi = mB + i * 16 + rr;
      float hv = hvec[b * 256 + mi];
      size_t rowo = ((size_t)b << 20) + (size_t)mi * 4096;
#pragma unroll
      for (int j = 0; j < 2; ++j)
        outF[rowo + nB + j * 16] = acc[i][j][rr] + hv;
    }
  }
}

// ---------------- gu: stats + wsv + G-rows-in-LDS + U-tile GEMM ----------------
// grid (4 n-tiles, 8 m-tiles, 8 b) = 256 blocks. Replaces r11's gfill2 + ugemm.
__global__ __launch_bounds__(256) void gu_k(const float* __restrict__ part,
                                            const float* __restrict__ sxpart,
                                            const float* __restrict__ gamma,
                                            const float* __restrict__ beta,
                                            const unsigned short* __restrict__ qkvw,
                                            float* __restrict__ avec,
                                            float* __restrict__ evec,
                                            float* __restrict__ wsv,
                                            unsigned short* __restrict__ Ubf) {
  __shared__ unsigned short As[4096];    // 8KB A staging
  __shared__ unsigned short Gs[16384];   // 32KB: 4 ks-buffers of G rows (Bs-swizzled)
  __shared__ float sav[256], sev[256], ssx[256], ssv[256];
  const int b = blockIdx.z;
  const int n0 = blockIdx.x << 6;   // U col tile == G row tile
  const int m0 = blockIdx.y << 6;   // U row tile (0..511)
  const int tid = threadIdx.x;
  const int l = tid & 63, w = tid >> 6;
  const int wm = w >> 1, wn = w & 1;
  const int r = tid >> 2;
  const int g0 = (tid & 3) * 2;
  const int w0 = r * 128 + ((g0 ^ (r & 7)) << 4);
  const int w1 = r * 128 + (((g0 + 1) ^ (r & 7)) << 4);
  int rdA[2], rdB[2];
#pragma unroll
  for (int i = 0; i < 2; ++i) {
    int rm = wm * 32 + i * 16 + (l & 15);
    rdA[i] = rm * 128 + (((l >> 4) ^ (rm & 7)) << 4);
    int rn = wn * 32 + i * 16 + (l & 15);
    rdB[i] = rn * 128 + (((l >> 4) ^ (rn & 7)) << 4);
  }

  // ---- phase A: GN stats (r11 gfill2 phase A) ----
  {
    const float* sp = sxpart + ((size_t)(b * 256 + tid) << 6);
    float sxv = 0.f;
#pragma unroll 4
    for (int i = 0; i < 64; ++i) sxv += sp[i];
    float dg = 0.f;
#pragma unroll
    for (int s = 0; s < 8; ++s) dg += part[((size_t)(b * 8 + s) << 16) + tid * 257];
    float gs = sxv, g2 = dg;
#pragma unroll
    for (int off = 1; off < 16; off <<= 1) {
      gs += __shfl_xor(gs, off);
      g2 += __shfl_xor(g2, off);
    }
    const float inv = 1.f / 65536.f;
    float mu = gs * inv;
    float var = g2 * inv - mu * mu;
    float rstd = rsqrtf(var + EPS_GN);
    float av = gamma[tid] * rstd;
    float ev = beta[tid] - mu * av;
    sav[tid] = av; sev[tid] = ev; ssx[tid] = sxv;
    ssv[tid] = av * sxv + 4096.f * ev;
    if (blockIdx.x == 0 && blockIdx.y == 0) {
      avec[b * 256 + tid] = av;
      evec[b * 256 + tid] = ev;
    }
  }
  __syncthreads();

  // ---- phase B: wsv rows m0..m0+63 (n-tile 0 blocks only; 4 threads/row) ----
  if (blockIdx.x == 0) {
    const int row = m0 + (tid >> 2);
    const int seg = (tid & 3) * 64;
    const unsigned short* wr = qkvw + (size_t)row * 256 + seg;
    float acc = 0.f;
#pragma unroll
    for (int d = 0; d < 64; d += 8) {
      int4 v = *(const int4*)(wr + d);
      acc += blo((unsigned)v.x) * ssv[seg + d + 0] + bhi((unsigned)v.x) * ssv[seg + d + 1];
      acc += blo((unsigned)v.y) * ssv[seg + d + 2] + bhi((unsigned)v.y) * ssv[seg + d + 3];
      acc += blo((unsigned)v.z) * ssv[seg + d + 4] + bhi((unsigned)v.z) * ssv[seg + d + 5];
      acc += blo((unsigned)v.w) * ssv[seg + d + 6] + bhi((unsigned)v.w) * ssv[seg + d + 7];
    }
    acc += __shfl_xor(acc, 1);
    acc += __shfl_xor(acc, 2);
    if ((tid & 3) == 0) wsv[b * 512 + row] = acc;
  }

  // ---- phase C: G rows n0..n0+63 into Gs (ks-buffer = d>>6, Bs-swizzled) ----
  {
    const int rl = tid >> 4;              // 0..15 within sub-strip
    const int ds0 = (tid & 15) * 16;      // d start (0..240)
    const int ksbuf = ds0 >> 6;
    const int kl0 = ds0 & 63;
    for (int sub = 0; sub < 4; ++sub) {
      const int row_local = sub * 16 + rl;
      const int c = n0 + row_local;
      const float ac = sav[c], ec = sev[c], sxc = ssx[c];
      float S[16];
#pragma unroll
      for (int q = 0; q < 16; ++q) S[q] = 0.f;
      for (int s = 0; s < 8; ++s) {
        const float* pp = part + (((size_t)(b * 8 + s)) << 16) + (size_t)c * 256 + ds0;
#pragma unroll
        for (int q4 = 0; q4 < 4; ++q4) {
          float4 v = *(const float4*)(pp + q4 * 4);
          S[q4 * 4 + 0] += v.x; S[q4 * 4 + 1] += v.y;
          S[q4 * 4 + 2] += v.z; S[q4 * 4 + 3] += v.w;
        }
      }
      unsigned pk[8];
#pragma unroll
      for (int q = 0; q < 8; ++q) {
        int d0_ = ds0 + 2 * q, d1_ = ds0 + 2 * q + 1;
        float gv0 = ac * sav[d0_] * S[2 * q]     + ac * sev[d0_] * sxc +
                    ec * sav[d0_] * ssx[d0_]     + 4096.f * ec * sev[d0_];
        float gv1 = ac * sav[d1_] * S[2 * q + 1] + ac * sev[d1_] * sxc +
                    ec * sav[d1_] * ssx[d1_]     + 4096.f * ec * sev[d1_];
        pk[q] = f2bf(gv0) | ((unsigned)f2bf(gv1) << 16);
      }
      const int base = ksbuf * 8192 + row_local * 128;
      const int slot0 = base + ((((kl0 >> 3) + 0) ^ (row_local & 7)) << 4);
      const int slot1 = base + ((((kl0 >> 3) + 1) ^ (row_local & 7)) << 4);
      *(int4*)((char*)Gs + slot0) = make_int4((int)pk[0], (int)pk[1], (int)pk[2], (int)pk[3]);
      *(int4*)((char*)Gs + slot1) = make_int4((int)pk[4], (int)pk[5], (int)pk[6], (int)pk[7]);
    }
  }
  __syncthreads();

  // ---- phase D: U tile = qkvw rows m0.. @ Gs (B frags from LDS; r12-verified read) ----
  f32x4 zero = {0.f, 0.f, 0.f, 0.f};
  f32x4 acc2[2][2] = {{zero, zero}, {zero, zero}};
  {
    const unsigned short* aG = qkvw + (size_t)(m0 + r) * 256 + (tid & 3) * 16;
    for (int ks = 0; ks < 4; ++ks) {
      int4 a0 = *(const int4*)aG, a1 = *(const int4*)(aG + 8);
      aG += 64;
      __syncthreads();
      *(int4*)((char*)As + w0) = a0; *(int4*)((char*)As + w1) = a1;
      __syncthreads();
#pragma unroll
      for (int kk = 0; kk < 2; ++kk) {
        bf16x8 af[2], bf_[2];
#pragma unroll
        for (int i = 0; i < 2; ++i) {
          af[i]  = *(const bf16x8*)((const char*)As + (rdA[i] ^ (kk << 6)));
          bf_[i] = *(const bf16x8*)((const char*)Gs + ks * 8192 + (rdB[i] ^ (kk << 6)));
        }
#pragma unroll
        for (int i = 0; i < 2; ++i)
#pragma unroll
          for (int j = 0; j < 2; ++j)
            acc2[i][j] = __builtin_amdgcn_mfma_f32_16x16x32_bf16(af[i], bf_[j], acc2[i][j], 0, 0, 0);
      }
    }
  }
  const int mB = m0 + wm * 32 + ((l >> 4) << 2);
  const int nB = n0 + wn * 32 + (l & 15);
  unsigned short* pu = Ubf + ((size_t)b << 17);
#pragma unroll
  for (int i = 0; i < 2; ++i)
#pragma unroll
    for (int rr = 0; rr < 4; ++rr)
#pragma unroll
      for (int j = 0; j < 2; ++j)
        pu[(size_t)(mB + i * 16 + rr) * 256 + nB + j * 16] = f2bf(acc2[i][j][rr]);
}

// ---------------- Y1 = Wv^T A^T  (bf16 out) + hvec base on y==0 blocks (r11-verified) ----------------
__global__ __launch_bounds__(256) void y1h_k(const unsigned short* __restrict__ wvt,
                                             const unsigned short* __restrict__ Abf,
                                             const float* __restrict__ abv,
                                             const float* __restrict__ proj_w,
                                             const float* __restrict__ proj_b,
                                             unsigned short* __restrict__ Y1,
                                             float* __restrict__ hvec) {
  __shared__ unsigned short As[4096];
  __shared__ unsigned short Bs[4096];
  __shared__ float abl[256];
  const int b = blockIdx.z;
  const int m0 = blockIdx.y << 6, n0 = blockIdx.x << 6;
  NT64_BODY(wvt, 256, Abf + ((size_t)b << 16), 256, 4)
  unsigned short* pu = Y1 + ((size_t)b << 16);
#pragma unroll
  for (int i = 0; i < 2; ++i)
#pragma unroll
    for (int rr = 0; rr < 4; ++rr)
#pragma unroll
      for (int j = 0; j < 2; ++j)
        pu[(size_t)(mB + i * 16 + rr) * 256 + nB + j * 16] = f2bf(acc[i][j][rr]);
  if (blockIdx.y == 0) {
    abl[tid] = abv[b * 256 + tid];
    __syncthreads();
    const int t = n0 + (tid >> 2);
    const int qd = (tid & 3) * 64;
    const float* pr = proj_w + (size_t)t * 256 + qd;
    float s = 0.f;
#pragma unroll 8
    for (int i = 0; i < 64; ++i) s += pr[i] * abl[qd + i];
    s += __shfl_xor(s, 1);
    s += __shfl_xor(s, 2);
    if ((tid & 3) == 0) hvec[b * 256 + t] = proj_b[t] + s;
  }
}

// ---------------- F[t,d] = sum_i Pw[t,i] Y1[d,i]; Fbf = F*diag(a)+I; hvec += F e (r11-verified) ----------------
__global__ __launch_bounds__(256) void fgen_k(const unsigned short* __restrict__ pw,
                                              const unsigned short* __restrict__ Y1,
                                              const float* __restrict__ avec,
                                              const float* __restrict__ evec,
                                              unsigned short* __restrict__ Fbf,
                                              float* __restrict__ hvec) {
  __shared__ unsigned short As[4096];
  __shared__ unsigned short Bs[4096];
  const int b = blockIdx.z;
  const int m0 = blockIdx.y << 6, n0 = blockIdx.x << 6;
  NT64_BODY(pw, 256, Y1 + ((size_t)b << 16), 256, 4)
  __syncthreads();
  float* hred = (float*)As;
  if (tid < 64) hred[tid] = 0.f;
  __syncthreads();
#pragma unroll
  for (int i = 0; i < 2; ++i) {
#pragma unroll
    for (int rr = 0; rr < 4; ++rr) {
      int t = mB + i * 16 + rr;
      float hp = 0.f;
#pragma unroll
      for (int j = 0; j < 2; ++j) {
        int d = nB + j * 16;
        float f = acc[i][j][rr];
        float fa = f * avec[b * 256 + d] + (t == d ? 1.f : 0.f);
        Fbf[((size_t)b << 16) + (size_t)t * 256 + d] = f2bf(fa);
        hp += f * evec[b * 256 + d];
      }
      atomicAdd(&hred[t - m0], hp);
    }
  }
  __syncthreads();
  if (tid < 64) atomicAdd(&hvec[b * 256 + m0 + tid], hred[tid]);
}

// ---------------- fused logits GEMM + inline norms + softmax + A.bv (r9-verified) ----------------
__global__ __launch_bounds__(256) void logsm_k(
    const unsigned short* __restrict__ Ubf,   // [b][512][256]
    const unsigned short* __restrict__ qkvw,  // Wq rows at 0, Wk rows at +65536
    const float* __restrict__ wsv,
    const float* __restrict__ qkv_b, const float* __restrict__ temp,
    unsigned short* __restrict__ Abf, float* __restrict__ abv) {
  __shared__ unsigned short As[64 * 64];    // 8KB
  __shared__ unsigned short Bs[256 * 64];   // 32KB
  const int b = blockIdx.y, m0 = blockIdx.x * 64;
  const int tid = threadIdx.x;
  const int l = tid & 63, w = tid >> 6;
  const unsigned short* wk = qkvw + 65536;

  const int ar = tid >> 2, ac = tid & 3;
  const unsigned short* aG = Ubf + ((size_t)b << 17) + (size_t)(m0 + ar) * 256 + ac * 16;
  const unsigned short* bG = wk + (size_t)tid * 256;
  const int g0 = ac * 2;
  const int wA0 = ar * 128 + (((g0)     ^ (ar & 7)) << 4);
  const int wA1 = ar * 128 + (((g0 + 1) ^ (ar & 7)) << 4);
  int wBoff[8];
#pragma unroll
  for (int c = 0; c < 8; ++c) wBoff[c] = tid * 128 + ((c ^ (tid & 7)) << 4);

  int rdA;
  { int rm = w * 16 + (l & 15); rdA = rm * 128 + (((l >> 4) ^ (rm & 7)) << 4); }
  int rdB[16];
#pragma unroll
  for (int nf = 0; nf < 16; ++nf) {
    int rn = nf * 16 + (l & 15);
    rdB[nf] = rn * 128 + (((l >> 4) ^ (rn & 7)) << 4);
  }

  f32x4 zero = {0.f, 0.f, 0.f, 0.f};
  f32x4 acc[16];
#pragma unroll
  for (int nf = 0; nf < 16; ++nf) acc[nf] = zero;

  for (int ks = 0; ks < 4; ++ks) {
    int4 a0 = *(const int4*)aG;
    int4 a1 = *(const int4*)(aG + 8);
    int4 bv[8];
#pragma unroll
    for (int c = 0; c < 8; ++c) bv[c] = *(const int4*)(bG + c * 8);
    aG += 64; bG += 64;
    __syncthreads();
    *(int4*)((char*)As + wA0) = a0;
    *(int4*)((char*)As + wA1) = a1;
#pragma unroll
    for (int c = 0; c < 8; ++c) *(int4*)((char*)Bs + wBoff[c]) = bv[c];
    __syncthreads();
#pragma unroll
    for (int kk = 0; kk < 2; ++kk) {
      bf16x8 af = *(const bf16x8*)((const char*)As + (rdA ^ (kk << 6)));
#pragma unroll
      for (int nf = 0; nf < 16; ++nf) {
        bf16x8 bf_ = *(const bf16x8*)((const char*)Bs + (rdB[nf] ^ (kk << 6)));
        acc[nf] = __builtin_amdgcn_mfma_f32_16x16x32_bf16(af, bf_, acc[nf], 0, 0, 0);
      }
    }
  }

  __syncthreads();
  float* sKs  = (float*)As;
  float* sWks = sKs + 256;
  float* sBk  = sWks + 256;
  float* sBv  = sBk + 256;
  float* sQs  = sBv + 256;
  {
    const unsigned short* ur = Ubf + ((size_t)b << 17) + (size_t)(256 + tid) * 256;
    const unsigned short* wr = wk + (size_t)tid * 256;
    float dot = 0.f;
    for (int dd = 0; dd < 256; dd += 8) {
      int4 uv = *(const int4*)(ur + dd);
      int4 wv = *(const int4*)(wr + dd);
      dot += blo((unsigned)uv.x) * blo((unsigned)wv.x) + bhi((unsigned)uv.x) * bhi((unsigned)wv.x);
      dot += blo((unsigned)uv.y) * blo((unsigned)wv.y) + bhi((unsigned)uv.y) * bhi((unsigned)wv.y);
      dot += blo((unsigned)uv.z) * blo((unsigned)wv.z) + bhi((unsigned)uv.z) * bhi((unsigned)wv.z);
      dot += blo((unsigned)uv.w) * blo((unsigned)wv.w) + bhi((unsigned)uv.w) * bhi((unsigned)wv.w);
    }
    float bk = qkv_b[256 + tid];
    float wks = wsv[b * 512 + 256 + tid];
    float n2 = dot + 2.f * bk * wks + 4096.f * bk * bk;
    sKs[tid]  = 1.f / fmaxf(sqrtf(fmaxf(n2, 0.f)), EPS_L2);
    sWks[tid] = wks;
    sBk[tid]  = bk;
    sBv[tid]  = qkv_b[512 + tid];
  }
  if (tid < 64) {
    int m = m0 + tid;
    const unsigned short* ur = Ubf + ((size_t)b << 17) + (size_t)m * 256;
    const unsigned short* wr = qkvw + (size_t)m * 256;
    float dot = 0.f;
    for (int dd = 0; dd < 256; dd += 8) {
      int4 uv = *(const int4*)(ur + dd);
      int4 wv = *(const int4*)(wr + dd);
      dot += blo((unsigned)uv.x) * blo((unsigned)wv.x) + bhi((unsigned)uv.x) * bhi((unsigned)wv.x);
      dot += blo((unsigned)uv.y) * blo((unsigned)wv.y) + bhi((unsigned)uv.y) * bhi((unsigned)wv.y);
      dot += blo((unsigned)uv.z) * blo((unsigned)wv.z) + bhi((unsigned)uv.z) * bhi((unsigned)wv.z);
      dot += blo((unsigned)uv.w) * blo((unsigned)wv.w) + bhi((unsigned)uv.w) * bhi((unsigned)wv.w);
    }
    float bq = qkv_b[m], wqs = wsv[b * 512 + m];
    float n2 = dot + 2.f * bq * wqs + 4096.f * bq * bq;
    sQs[tid] = 1.f / fmaxf(sqrtf(fmaxf(n2, 0.f)), EPS_L2);
  }
  __syncthreads();

  const float T = temp[0];
  const int lrow = w * 16 + ((l >> 4) << 2);
  const int mrow = m0 + lrow;
  float ks_c[16], wks_c[16], bk_c[16], bv_c[16];
#pragma unroll
  for (int nf = 0; nf < 16; ++nf) {
    int n = nf * 16 + (l & 15);
    ks_c[nf] = sKs[n]; wks_c[nf] = sWks[n]; bk_c[nf] = sBk[n]; bv_c[nf] = sBv[n];
  }
#pragma unroll
  for (int rr = 0; rr < 4; ++rr) {
    int m = mrow + rr;
    float qs = sQs[lrow + rr], wqs = wsv[b * 512 + m], bq = qkv_b[m];
    float sc = T * qs;
#pragma unroll
    for (int nf = 0; nf < 16; ++nf)
      acc[nf][rr] = sc * ks_c[nf] *
                    (acc[nf][rr] + bq * wks_c[nf] + bk_c[nf] * wqs + 4096.f * bq * bk_c[nf]);
    float mx = acc[0][rr];
#pragma unroll
    for (int nf = 1; nf < 16; ++nf) mx = fmaxf(mx, acc[nf][rr]);
    mx = fmaxf(mx, __shfl_xor(mx, 1));
    mx = fmaxf(mx, __shfl_xor(mx, 2));
    mx = fmaxf(mx, __shfl_xor(mx, 4));
    mx = fmaxf(mx, __shfl_xor(mx, 8));
    float s = 0.f, ab = 0.f;
#pragma unroll
    for (int nf = 0; nf < 16; ++nf) {
      float e = __expf(acc[nf][rr] - mx);
      acc[nf][rr] = e;
      s += e; ab += e * bv_c[nf];
    }
#pragma unroll
    for (int off = 1; off < 16; off <<= 1) {
      s += __shfl_xor(s, off);
      ab += __shfl_xor(ab, off);
    }
    float inv = 1.f / s;
    unsigned short* arow = Abf + ((size_t)b << 16) + (size_t)m * 256 + (l & 15);
#pragma unroll
    for (int nf = 0; nf < 16; ++nf)
      arow[nf * 16] = f2bf(acc[nf][rr] * inv);
    if ((l & 15) == 0) abv[b * 256 + m] = ab * inv;
  }
}

}  // namespace

extern "C" void kernel_launch(void* const* d_in, const int* in_sizes, int n_in,
                              void* d_out, int out_size, void* d_ws, size_t ws_size,
                              hipStream_t stream) {
  const float* x      = (const float*)d_in[0];
  const float* gamma  = (const float*)d_in[1];
  const float* beta   = (const float*)d_in[2];
  const float* qkv_w  = (const float*)d_in[3];
  const float* qkv_b  = (const float*)d_in[4];
  const float* temp   = (const float*)d_in[5];
  const float* proj_w = (const float*)d_in[6];
  const float* proj_b = (const float*)d_in[7];
  float* out = (float*)d_out;

  char* ws = (char*)d_ws;
  const size_t MB = 1048576;
  unsigned short* qkvw_bf = (unsigned short*)(ws);             // 384KB
  unsigned short* pw_bf   = (unsigned short*)(ws + 0x60000);   // 128KB
  unsigned short* wvt_bf  = (unsigned short*)(ws + 0x80000);   // 128KB
  float* avec  = (float*)(ws + 0xA0000);
  float* evec  = (float*)(ws + 0xA2000);
  float* wsv   = (float*)(ws + 0xA6000);
  float* hvec  = (float*)(ws + 0xAA000);
  float* abv   = (float*)(ws + 0xAC000);
  float* sxpart = (float*)(ws + 1 * MB);                   // 512KB
  float* part   = (float*)(ws + 2 * MB);                   // 16MB
  unsigned short* Ubf = (unsigned short*)(ws + 19 * MB);   // 2MB
  unsigned short* Abf = (unsigned short*)(ws + 21 * MB);   // 1MB
  unsigned short* Y1  = (unsigned short*)(ws + 22 * MB);   // 1MB
  unsigned short* Fbf = (unsigned short*)(ws + 23 * MB);   // 1MB
  unsigned short* xbf = (unsigned short*)(ws + 24 * MB);   // 16MB
  unsigned short* xT  = (unsigned short*)(ws + 40 * MB);   // 16MB
  if (ws_size < 56 * MB) return;

  // 1. x prep + weight conversions
  prep_k<<<2320, 256, 0, stream>>>(x, qkv_w, proj_w, xbf, xT, sxpart,
                                   qkvw_bf, pw_bf, wvt_bf);

  // 2. Sxx = X X^T (64^2 tiles, split-K 8 -> 1024 blocks, 4/CU)
  sxx64_k<<<dim3(4, 4, 64), 256, 0, stream>>>(xbf, part);

  // 3. gu: stats + wsv + G-in-LDS + U GEMM (replaces gfill2 + ugemm)
  gu_k<<<dim3(4, 8, 8), 256, 0, stream>>>(part, sxpart, gamma, beta, qkvw_bf,
                                          avec, evec, wsv, Ubf);

  // 4. logits + inline norms + softmax + A.bv
  logsm_k<<<dim3(4, 8), 256, 0, stream>>>(Ubf, qkvw_bf, wsv, qkv_b, temp, Abf, abv);

  // 5. Y1 = Wv^T A^T (+ hvec base on y==0)
  y1h_k<<<dim3(4, 4, 8), 256, 0, stream>>>(wvt_bf, Abf, abv, proj_w, proj_b, Y1, hvec);

  // 6. F + Fbf(=F diag(a)+I) + hvec += F e
  fgen_k<<<dim3(4, 4, 8), 256, 0, stream>>>(pw_bf, Y1, avec, evec, Fbf, hvec);

  // 7. out = F~ @ X + h~ (2048 blocks, 8/CU)
  out64_k<<<dim3(64, 4, 8), 256, 0, stream>>>(Fbf, xT, hvec, out);
}

// Round 14
// 106.792 us; speedup vs baseline: 1.0477x; 1.0313x over previous
//
#include <hip/hip_runtime.h>
#include <hip/hip_bf16.h>

namespace {

constexpr float EPS_GN = 1e-6f;
constexpr float EPS_L2 = 1e-12f;

typedef __attribute__((ext_vector_type(8))) short bf16x8;
typedef __attribute__((ext_vector_type(4))) float f32x4;

__device__ __forceinline__ unsigned short f2bf(float f) {
  union { __hip_bfloat16 h; unsigned short u; } cv;
  cv.h = __float2bfloat16(f);
  return cv.u;
}
__device__ __forceinline__ float blo(unsigned u) { return __uint_as_float(u << 16); }
__device__ __forceinline__ float bhi(unsigned u) { return __uint_as_float(u & 0xffff0000u); }

// ---------------- prep: x->xbf/xT/sxpart AND weight conversions (r9-verified) ----------------
__global__ __launch_bounds__(256) void prep_k(const float* __restrict__ x,
                                              const float* __restrict__ qkv_w,
                                              const float* __restrict__ proj_w,
                                              unsigned short* __restrict__ xbf,
                                              unsigned short* __restrict__ xT,
                                              float* __restrict__ sxpart,
                                              unsigned short* __restrict__ qkvw_bf,
                                              unsigned short* __restrict__ pw_bf,
                                              unsigned short* __restrict__ wvt_bf) {
  __shared__ char shm[16640];
  const int bid = blockIdx.x, t = threadIdx.x;
  if (bid < 2048) {
    unsigned short (*tl)[68] = (unsigned short (*)[68])shm;
    const int b = bid >> 8, cy = (bid >> 6) & 3, nx = bid & 63;
    const int c0 = cy * 64, n0 = nx * 64;
    const int cl = t >> 2, ns = (t & 3) * 16;
    const float* xp = x + ((size_t)b << 20) + (size_t)(c0 + cl) * 4096 + n0 + ns;
    unsigned pk[8];
    float s = 0.f;
#pragma unroll
    for (int q = 0; q < 4; ++q) {
      float4 v = *(const float4*)(xp + q * 4);
      s += v.x + v.y + v.z + v.w;
      pk[2 * q + 0] = f2bf(v.x) | ((unsigned)f2bf(v.y) << 16);
      pk[2 * q + 1] = f2bf(v.z) | ((unsigned)f2bf(v.w) << 16);
    }
    unsigned short* xo = xbf + ((size_t)b << 20) + (size_t)(c0 + cl) * 4096 + n0 + ns;
    *(int4*)xo = make_int4((int)pk[0], (int)pk[1], (int)pk[2], (int)pk[3]);
    *(int4*)(xo + 8) = make_int4((int)pk[4], (int)pk[5], (int)pk[6], (int)pk[7]);
#pragma unroll
    for (int q = 0; q < 8; ++q)
      *(unsigned*)(&tl[cl][ns + 2 * q]) = pk[q];
    s += __shfl_xor(s, 1);
    s += __shfl_xor(s, 2);
    if ((t & 3) == 0)
      sxpart[((size_t)((b * 4 + cy) * 64 + cl)) * 64 + nx] = s;
    __syncthreads();
    const int nl = t >> 2, cs2 = (t & 3) * 16;
    unsigned pk2[8];
#pragma unroll
    for (int q = 0; q < 8; ++q)
      pk2[q] = (unsigned)(unsigned short)tl[cs2 + 2 * q][nl] |
               ((unsigned)(unsigned short)tl[cs2 + 2 * q + 1][nl] << 16);
    unsigned short* to = xT + ((size_t)((b << 12) + n0 + nl)) * 256 + c0 + cs2;
    *(int4*)to = make_int4((int)pk2[0], (int)pk2[1], (int)pk2[2], (int)pk2[3]);
    *(int4*)(to + 8) = make_int4((int)pk2[4], (int)pk2[5], (int)pk2[6], (int)pk2[7]);
    return;
  }
  const int cb = bid - 2048;
  if (cb < 256) {
    const float* src = (cb < 192) ? qkv_w : proj_w;
    unsigned short* dst = (cb < 192) ? qkvw_bf : pw_bf;
    int i = (cb < 192 ? cb : cb - 192) * 256 + t;
    float4 v = ((const float4*)src)[i];
    unsigned p0 = f2bf(v.x) | ((unsigned)f2bf(v.y) << 16);
    unsigned p1 = f2bf(v.z) | ((unsigned)f2bf(v.w) << 16);
    ((int2*)dst)[i] = make_int2((int)p0, (int)p1);
    return;
  }
  float (*tlf)[65] = (float (*)[65])shm;
  const int tb = cb - 256;
  const int j0 = (tb >> 2) * 64, d0 = (tb & 3) * 64;
  const float* src = qkv_w + 512 * 256;
  const int jr = t >> 2, ds = (t & 3) * 16;
#pragma unroll
  for (int q = 0; q < 4; ++q) {
    float4 v = *(const float4*)(src + (size_t)(j0 + jr) * 256 + d0 + ds + q * 4);
    tlf[jr][ds + q * 4 + 0] = v.x; tlf[jr][ds + q * 4 + 1] = v.y;
    tlf[jr][ds + q * 4 + 2] = v.z; tlf[jr][ds + q * 4 + 3] = v.w;
  }
  __syncthreads();
  const int dr = t >> 2, js = (t & 3) * 16;
  unsigned pk[8];
#pragma unroll
  for (int q = 0; q < 8; ++q)
    pk[q] = f2bf(tlf[js + 2 * q][dr]) | ((unsigned)f2bf(tlf[js + 2 * q + 1][dr]) << 16);
  unsigned short* dp = wvt_bf + (size_t)(d0 + dr) * 256 + j0 + js;
  *(int4*)dp = make_int4((int)pk[0], (int)pk[1], (int)pk[2], (int)pk[3]);
  *(int4*)(dp + 8) = make_int4((int)pk[4], (int)pk[5], (int)pk[6], (int)pk[7]);
}

// ---------------- 64x64-tile NT-GEMM macro body (verified r4-r11) ----------------
#define NT64_BODY(APTR, ALDA, BPTR, BLDB, KSTEPS)                                   \
  const int tid = threadIdx.x;                                                      \
  const int l = tid & 63, w = tid >> 6;                                             \
  const int wm = w >> 1, wn = w & 1;                                                \
  const int r = tid >> 2;                                                           \
  const unsigned short* aG = (APTR) + (size_t)(m0 + r) * (ALDA) + (tid & 3) * 16;   \
  const unsigned short* bG = (BPTR) + (size_t)(n0 + r) * (BLDB) + (tid & 3) * 16;   \
  const int g0 = (tid & 3) * 2;                                                     \
  const int w0 = r * 128 + (((g0)     ^ (r & 7)) << 4);                             \
  const int w1 = r * 128 + (((g0 + 1) ^ (r & 7)) << 4);                             \
  int rdA[2], rdB[2];                                                               \
  _Pragma("unroll")                                                                 \
  for (int i = 0; i < 2; ++i) {                                                     \
    int rm = wm * 32 + i * 16 + (l & 15);                                           \
    rdA[i] = rm * 128 + (((l >> 4) ^ (rm & 7)) << 4);                               \
    int rn = wn * 32 + i * 16 + (l & 15);                                           \
    rdB[i] = rn * 128 + (((l >> 4) ^ (rn & 7)) << 4);                               \
  }                                                                                 \
  f32x4 zero = {0.f, 0.f, 0.f, 0.f};                                                \
  f32x4 acc[2][2] = {{zero, zero}, {zero, zero}};                                   \
  for (int ks = 0; ks < (KSTEPS); ++ks) {                                           \
    int4 a0 = *(const int4*)aG, a1 = *(const int4*)(aG + 8);                        \
    int4 b0 = *(const int4*)bG, b1 = *(const int4*)(bG + 8);                        \
    aG += 64; bG += 64;                                                             \
    __syncthreads();                                                                \
    *(int4*)((char*)As + w0) = a0; *(int4*)((char*)As + w1) = a1;                   \
    *(int4*)((char*)Bs + w0) = b0; *(int4*)((char*)Bs + w1) = b1;                   \
    __syncthreads();                                                                \
    _Pragma("unroll")                                                               \
    for (int kk = 0; kk < 2; ++kk) {                                                \
      bf16x8 af[2], bf_[2];                                                         \
      _Pragma("unroll")                                                             \
      for (int i = 0; i < 2; ++i) {                                                 \
        af[i]  = *(const bf16x8*)((const char*)As + (rdA[i] ^ (kk << 6)));          \
        bf_[i] = *(const bf16x8*)((const char*)Bs + (rdB[i] ^ (kk << 6)));          \
      }                                                                             \
      _Pragma("unroll")                                                             \
      for (int i = 0; i < 2; ++i)                                                   \
        _Pragma("unroll")                                                           \
        for (int j = 0; j < 2; ++j)                                                 \
          acc[i][j] = __builtin_amdgcn_mfma_f32_16x16x32_bf16(af[i], bf_[j],        \
                                                              acc[i][j], 0, 0, 0); \
    }                                                                               \
  }                                                                                 \
  const int mB = m0 + wm * 32 + ((l >> 4) << 2);                                    \
  const int nB = n0 + wn * 32 + (l & 15);

// ---------------- Sxx = X X^T, split-K 8: grid (4,4,64) (r9-verified) ----------------
__global__ __launch_bounds__(256) void sxx64_k(const unsigned short* __restrict__ xbf,
                                               float* __restrict__ part) {
  __shared__ unsigned short As[4096];
  __shared__ unsigned short Bs[4096];
  const int z = blockIdx.z;
  const int b = z >> 3, sl = z & 7;
  const int m0 = blockIdx.y << 6, n0 = blockIdx.x << 6;
  const unsigned short* base = xbf + ((size_t)b << 20) + (size_t)sl * 512;
  NT64_BODY(base, 4096, base, 4096, 8)
  float* po = part + ((size_t)z << 16);
#pragma unroll
  for (int i = 0; i < 2; ++i)
#pragma unroll
    for (int rr = 0; rr < 4; ++rr)
#pragma unroll
      for (int j = 0; j < 2; ++j)
        po[(size_t)(mB + i * 16 + rr) * 256 + nB + j * 16] = acc[i][j][rr];
}

// ---------------- out = F~ @ X + h~: grid (64,4,8) (r9-verified) ----------------
__global__ __launch_bounds__(256) void out64_k(const unsigned short* __restrict__ Fbf,
                                               const unsigned short* __restrict__ xT,
                                               const float* __restrict__ hvec,
                                               float* __restrict__ outF) {
  __shared__ unsigned short As[4096];
  __shared__ unsigned short Bs[4096];
  const int b = blockIdx.z;
  const int m0 = blockIdx.y << 6, n0 = blockIdx.x << 6;
  NT64_BODY(Fbf + ((size_t)b << 16), 256, xT + ((size_t)b << 20), 256, 4)
#pragma unroll
  for (int i = 0; i < 2; ++i) {
#pragma unroll
    for (int rr = 0; rr < 4; ++rr) {
      int mi = mB + i * 16 + rr;
      float hv = hvec[b * 256 + mi];
      size_t rowo = ((size_t)b << 20) + (size_t)mi * 4096;
#pragma unroll
      for (int j = 0; j < 2; ++j)
        outF[rowo + nB + j * 16] = acc[i][j][rr] + hv;
    }
  }
}

// ---------------- gfill2: per-block GN stats + G tile + wsv slice (r11-verified) ----------------
__global__ __launch_bounds__(256) void gfill2_k(const float* __restrict__ part,
                                                const float* __restrict__ sxpart,
                                                const float* __restrict__ gamma,
                                                const float* __restrict__ beta,
                                                const unsigned short* __restrict__ qkvw_bf,
                                                float* __restrict__ avec,
                                                float* __restrict__ evec,
                                                float* __restrict__ wsv,
                                                unsigned short* __restrict__ Gbf) {
  __shared__ float sav[256], sev[256], ssx[256], ssv[256];
  const int b = blockIdx.y, t = threadIdx.x;

  // phase A: GN stats for channel c = t
  {
    const float* sp = sxpart + ((size_t)(b * 256 + t) << 6);
    float sxv = 0.f;
#pragma unroll 4
    for (int i = 0; i < 64; ++i) sxv += sp[i];
    float dg = 0.f;
#pragma unroll
    for (int s = 0; s < 8; ++s) dg += part[((size_t)(b * 8 + s) << 16) + t * 257];
    float gs = sxv, g2 = dg;
#pragma unroll
    for (int off = 1; off < 16; off <<= 1) {
      gs += __shfl_xor(gs, off);
      g2 += __shfl_xor(g2, off);
    }
    const float inv = 1.f / 65536.f;
    float mu = gs * inv;
    float var = g2 * inv - mu * mu;
    float rstd = rsqrtf(var + EPS_GN);
    float av = gamma[t] * rstd;
    float ev = beta[t] - mu * av;
    sav[t] = av; sev[t] = ev; ssx[t] = sxv;
    ssv[t] = av * sxv + 4096.f * ev;
    if (blockIdx.x == 0) {
      avec[b * 256 + t] = av;
      evec[b * 256 + t] = ev;
    }
  }
  __syncthreads();

  // phase B: wsv slice (32 rows per block, 8 threads per row)
  {
    const int row = blockIdx.x * 32 + (t >> 3);
    const int seg = (t & 7) * 32;
    const unsigned short* wr = qkvw_bf + (size_t)row * 256 + seg;
    float acc = 0.f;
#pragma unroll
    for (int d = 0; d < 32; d += 8) {
      int4 v = *(const int4*)(wr + d);
      acc += blo((unsigned)v.x) * ssv[seg + d + 0] + bhi((unsigned)v.x) * ssv[seg + d + 1];
      acc += blo((unsigned)v.y) * ssv[seg + d + 2] + bhi((unsigned)v.y) * ssv[seg + d + 3];
      acc += blo((unsigned)v.z) * ssv[seg + d + 4] + bhi((unsigned)v.z) * ssv[seg + d + 5];
      acc += blo((unsigned)v.w) * ssv[seg + d + 6] + bhi((unsigned)v.w) * ssv[seg + d + 7];
    }
    acc += __shfl_xor(acc, 1);
    acc += __shfl_xor(acc, 2);
    acc += __shfl_xor(acc, 4);
    if ((t & 7) == 0) wsv[b * 512 + row] = acc;
  }

  // phase C: G tile
  {
    const int rr_ = blockIdx.x * 16 + (t >> 4);
    const int cs = (t & 15) * 16;
    const float ac = sav[rr_], ec = sev[rr_], sxc = ssx[rr_];
    unsigned pk[8];
#pragma unroll
    for (int q = 0; q < 8; ++q) {
      unsigned lohi[2];
#pragma unroll
      for (int h = 0; h < 2; ++h) {
        int d = cs + 2 * q + h;
        float S = 0.f;
#pragma unroll
        for (int s = 0; s < 8; ++s)
          S += part[(((size_t)(b * 8 + s)) << 16) + (size_t)rr_ * 256 + d];
        float gv = ac * sav[d] * S + ac * sev[d] * sxc + ec * sav[d] * ssx[d] +
                   4096.f * ec * sev[d];
        lohi[h] = f2bf(gv);
      }
      pk[q] = lohi[0] | (lohi[1] << 16);
    }
    unsigned short* gp = Gbf + ((size_t)b << 16) + (size_t)rr_ * 256 + cs;
    *(int4*)gp = make_int4((int)pk[0], (int)pk[1], (int)pk[2], (int)pk[3]);
    *(int4*)(gp + 8) = make_int4((int)pk[4], (int)pk[5], (int)pk[6], (int)pk[7]);
  }
}

// ---------------- U = [Wq;Wk] @ G  (bf16 out) ----------------
__global__ __launch_bounds__(256) void ugemm_k(const unsigned short* __restrict__ qkvw,
                                               const unsigned short* __restrict__ Gbf,
                                               unsigned short* __restrict__ Ubf) {
  __shared__ unsigned short As[4096];
  __shared__ unsigned short Bs[4096];
  const int b = blockIdx.z;
  const int m0 = blockIdx.y << 6, n0 = blockIdx.x << 6;
  NT64_BODY(qkvw, 256, Gbf + ((size_t)b << 16), 256, 4)
  unsigned short* pu = Ubf + ((size_t)b << 17);
#pragma unroll
  for (int i = 0; i < 2; ++i)
#pragma unroll
    for (int rr = 0; rr < 4; ++rr)
#pragma unroll
      for (int j = 0; j < 2; ++j)
        pu[(size_t)(mB + i * 16 + rr) * 256 + nB + j * 16] = f2bf(acc[i][j][rr]);
}

// ---------------- Y1 = Wv^T A^T  (bf16 out) + hvec base on y==0 blocks ----------------
__global__ __launch_bounds__(256) void y1h_k(const unsigned short* __restrict__ wvt,
                                             const unsigned short* __restrict__ Abf,
                                             const float* __restrict__ abv,
                                             const float* __restrict__ proj_w,
                                             const float* __restrict__ proj_b,
                                             unsigned short* __restrict__ Y1,
                                             float* __restrict__ hvec) {
  __shared__ unsigned short As[4096];
  __shared__ unsigned short Bs[4096];
  __shared__ float abl[256];
  const int b = blockIdx.z;
  const int m0 = blockIdx.y << 6, n0 = blockIdx.x << 6;
  NT64_BODY(wvt, 256, Abf + ((size_t)b << 16), 256, 4)
  unsigned short* pu = Y1 + ((size_t)b << 16);
#pragma unroll
  for (int i = 0; i < 2; ++i)
#pragma unroll
    for (int rr = 0; rr < 4; ++rr)
#pragma unroll
      for (int j = 0; j < 2; ++j)
        pu[(size_t)(mB + i * 16 + rr) * 256 + nB + j * 16] = f2bf(acc[i][j][rr]);
  if (blockIdx.y == 0) {
    abl[tid] = abv[b * 256 + tid];
    __syncthreads();
    const int t = n0 + (tid >> 2);
    const int qd = (tid & 3) * 64;
    const float* pr = proj_w + (size_t)t * 256 + qd;
    float s = 0.f;
#pragma unroll 8
    for (int i = 0; i < 64; ++i) s += pr[i] * abl[qd + i];
    s += __shfl_xor(s, 1);
    s += __shfl_xor(s, 2);
    if ((tid & 3) == 0) hvec[b * 256 + t] = proj_b[t] + s;
  }
}

// ---------------- F[t,d] = sum_i Pw[t,i] Y1[d,i]; Fbf = F*diag(a)+I; hvec += F e ----------------
__global__ __launch_bounds__(256) void fgen_k(const unsigned short* __restrict__ pw,
                                              const unsigned short* __restrict__ Y1,
                                              const float* __restrict__ avec,
                                              const float* __restrict__ evec,
                                              unsigned short* __restrict__ Fbf,
                                              float* __restrict__ hvec) {
  __shared__ unsigned short As[4096];
  __shared__ unsigned short Bs[4096];
  const int b = blockIdx.z;
  const int m0 = blockIdx.y << 6, n0 = blockIdx.x << 6;
  NT64_BODY(pw, 256, Y1 + ((size_t)b << 16), 256, 4)
  __syncthreads();
  float* hred = (float*)As;
  if (tid < 64) hred[tid] = 0.f;
  __syncthreads();
#pragma unroll
  for (int i = 0; i < 2; ++i) {
#pragma unroll
    for (int rr = 0; rr < 4; ++rr) {
      int t = mB + i * 16 + rr;
      float hp = 0.f;
#pragma unroll
      for (int j = 0; j < 2; ++j) {
        int d = nB + j * 16;
        float f = acc[i][j][rr];
        float fa = f * avec[b * 256 + d] + (t == d ? 1.f : 0.f);
        Fbf[((size_t)b << 16) + (size_t)t * 256 + d] = f2bf(fa);
        hp += f * evec[b * 256 + d];
      }
      atomicAdd(&hred[t - m0], hp);
    }
  }
  __syncthreads();
  if (tid < 64) atomicAdd(&hvec[b * 256 + m0 + tid], hred[tid]);
}

// ---------------- fused logits GEMM + inline norms + softmax + A.bv (r9-verified) ----------------
__global__ __launch_bounds__(256) void logsm_k(
    const unsigned short* __restrict__ Ubf,   // [b][512][256]
    const unsigned short* __restrict__ qkvw,  // Wq rows at 0, Wk rows at +65536
    const float* __restrict__ wsv,
    const float* __restrict__ qkv_b, const float* __restrict__ temp,
    unsigned short* __restrict__ Abf, float* __restrict__ abv) {
  __shared__ unsigned short As[64 * 64];    // 8KB
  __shared__ unsigned short Bs[256 * 64];   // 32KB
  const int b = blockIdx.y, m0 = blockIdx.x * 64;
  const int tid = threadIdx.x;
  const int l = tid & 63, w = tid >> 6;
  const unsigned short* wk = qkvw + 65536;

  const int ar = tid >> 2, ac = tid & 3;
  const unsigned short* aG = Ubf + ((size_t)b << 17) + (size_t)(m0 + ar) * 256 + ac * 16;
  const unsigned short* bG = wk + (size_t)tid * 256;
  const int g0 = ac * 2;
  const int wA0 = ar * 128 + (((g0)     ^ (ar & 7)) << 4);
  const int wA1 = ar * 128 + (((g0 + 1) ^ (ar & 7)) << 4);
  int wBoff[8];
#pragma unroll
  for (int c = 0; c < 8; ++c) wBoff[c] = tid * 128 + ((c ^ (tid & 7)) << 4);

  int rdA;
  { int rm = w * 16 + (l & 15); rdA = rm * 128 + (((l >> 4) ^ (rm & 7)) << 4); }
  int rdB[16];
#pragma unroll
  for (int nf = 0; nf < 16; ++nf) {
    int rn = nf * 16 + (l & 15);
    rdB[nf] = rn * 128 + (((l >> 4) ^ (rn & 7)) << 4);
  }

  f32x4 zero = {0.f, 0.f, 0.f, 0.f};
  f32x4 acc[16];
#pragma unroll
  for (int nf = 0; nf < 16; ++nf) acc[nf] = zero;

  for (int ks = 0; ks < 4; ++ks) {
    int4 a0 = *(const int4*)aG;
    int4 a1 = *(const int4*)(aG + 8);
    int4 bv[8];
#pragma unroll
    for (int c = 0; c < 8; ++c) bv[c] = *(const int4*)(bG + c * 8);
    aG += 64; bG += 64;
    __syncthreads();
    *(int4*)((char*)As + wA0) = a0;
    *(int4*)((char*)As + wA1) = a1;
#pragma unroll
    for (int c = 0; c < 8; ++c) *(int4*)((char*)Bs + wBoff[c]) = bv[c];
    __syncthreads();
#pragma unroll
    for (int kk = 0; kk < 2; ++kk) {
      bf16x8 af = *(const bf16x8*)((const char*)As + (rdA ^ (kk << 6)));
#pragma unroll
      for (int nf = 0; nf < 16; ++nf) {
        bf16x8 bf_ = *(const bf16x8*)((const char*)Bs + (rdB[nf] ^ (kk << 6)));
        acc[nf] = __builtin_amdgcn_mfma_f32_16x16x32_bf16(af, bf_, acc[nf], 0, 0, 0);
      }
    }
  }

  __syncthreads();
  float* sKs  = (float*)As;
  float* sWks = sKs + 256;
  float* sBk  = sWks + 256;
  float* sBv  = sBk + 256;
  float* sQs  = sBv + 256;
  {
    const unsigned short* ur = Ubf + ((size_t)b << 17) + (size_t)(256 + tid) * 256;
    const unsigned short* wr = wk + (size_t)tid * 256;
    float dot = 0.f;
    for (int dd = 0; dd < 256; dd += 8) {
      int4 uv = *(const int4*)(ur + dd);
      int4 wv = *(const int4*)(wr + dd);
      dot += blo((unsigned)uv.x) * blo((unsigned)wv.x) + bhi((unsigned)uv.x) * bhi((unsigned)wv.x);
      dot += blo((unsigned)uv.y) * blo((unsigned)wv.y) + bhi((unsigned)uv.y) * bhi((unsigned)wv.y);
      dot += blo((unsigned)uv.z) * blo((unsigned)wv.z) + bhi((unsigned)uv.z) * bhi((unsigned)wv.z);
      dot += blo((unsigned)uv.w) * blo((unsigned)wv.w) + bhi((unsigned)uv.w) * bhi((unsigned)wv.w);
    }
    float bk = qkv_b[256 + tid];
    float wks = wsv[b * 512 + 256 + tid];
    float n2 = dot + 2.f * bk * wks + 4096.f * bk * bk;
    sKs[tid]  = 1.f / fmaxf(sqrtf(fmaxf(n2, 0.f)), EPS_L2);
    sWks[tid] = wks;
    sBk[tid]  = bk;
    sBv[tid]  = qkv_b[512 + tid];
  }
  if (tid < 64) {
    int m = m0 + tid;
    const unsigned short* ur = Ubf + ((size_t)b << 17) + (size_t)m * 256;
    const unsigned short* wr = qkvw + (size_t)m * 256;
    float dot = 0.f;
    for (int dd = 0; dd < 256; dd += 8) {
      int4 uv = *(const int4*)(ur + dd);
      int4 wv = *(const int4*)(wr + dd);
      dot += blo((unsigned)uv.x) * blo((unsigned)wv.x) + bhi((unsigned)uv.x) * bhi((unsigned)wv.x);
      dot += blo((unsigned)uv.y) * blo((unsigned)wv.y) + bhi((unsigned)uv.y) * bhi((unsigned)wv.y);
      dot += blo((unsigned)uv.z) * blo((unsigned)wv.z) + bhi((unsigned)uv.z) * bhi((unsigned)wv.z);
      dot += blo((unsigned)uv.w) * blo((unsigned)wv.w) + bhi((unsigned)uv.w) * bhi((unsigned)wv.w);
    }
    float bq = qkv_b[m], wqs = wsv[b * 512 + m];
    float n2 = dot + 2.f * bq * wqs + 4096.f * bq * bq;
    sQs[tid] = 1.f / fmaxf(sqrtf(fmaxf(n2, 0.f)), EPS_L2);
  }
  __syncthreads();

  const float T = temp[0];
  const int lrow = w * 16 + ((l >> 4) << 2);
  const int mrow = m0 + lrow;
  float ks_c[16], wks_c[16], bk_c[16], bv_c[16];
#pragma unroll
  for (int nf = 0; nf < 16; ++nf) {
    int n = nf * 16 + (l & 15);
    ks_c[nf] = sKs[n]; wks_c[nf] = sWks[n]; bk_c[nf] = sBk[n]; bv_c[nf] = sBv[n];
  }
#pragma unroll
  for (int rr = 0; rr < 4; ++rr) {
    int m = mrow + rr;
    float qs = sQs[lrow + rr], wqs = wsv[b * 512 + m], bq = qkv_b[m];
    float sc = T * qs;
#pragma unroll
    for (int nf = 0; nf < 16; ++nf)
      acc[nf][rr] = sc * ks_c[nf] *
                    (acc[nf][rr] + bq * wks_c[nf] + bk_c[nf] * wqs + 4096.f * bq * bk_c[nf]);
    float mx = acc[0][rr];
#pragma unroll
    for (int nf = 1; nf < 16; ++nf) mx = fmaxf(mx, acc[nf][rr]);
    mx = fmaxf(mx, __shfl_xor(mx, 1));
    mx = fmaxf(mx, __shfl_xor(mx, 2));
    mx = fmaxf(mx, __shfl_xor(mx, 4));
    mx = fmaxf(mx, __shfl_xor(mx, 8));
    float s = 0.f, ab = 0.f;
#pragma unroll
    for (int nf = 0; nf < 16; ++nf) {
      float e = __expf(acc[nf][rr] - mx);
      acc[nf][rr] = e;
      s += e; ab += e * bv_c[nf];
    }
#pragma unroll
    for (int off = 1; off < 16; off <<= 1) {
      s += __shfl_xor(s, off);
      ab += __shfl_xor(ab, off);
    }
    float inv = 1.f / s;
    unsigned short* arow = Abf + ((size_t)b << 16) + (size_t)m * 256 + (l & 15);
#pragma unroll
    for (int nf = 0; nf < 16; ++nf)
      arow[nf * 16] = f2bf(acc[nf][rr] * inv);
    if ((l & 15) == 0) abv[b * 256 + m] = ab * inv;
  }
}

}  // namespace

extern "C" void kernel_launch(void* const* d_in, const int* in_sizes, int n_in,
                              void* d_out, int out_size, void* d_ws, size_t ws_size,
                              hipStream_t stream) {
  const float* x      = (const float*)d_in[0];
  const float* gamma  = (const float*)d_in[1];
  const float* beta   = (const float*)d_in[2];
  const float* qkv_w  = (const float*)d_in[3];
  const float* qkv_b  = (const float*)d_in[4];
  const float* temp   = (const float*)d_in[5];
  const float* proj_w = (const float*)d_in[6];
  const float* proj_b = (const float*)d_in[7];
  float* out = (float*)d_out;

  char* ws = (char*)d_ws;
  const size_t MB = 1048576;
  unsigned short* qkvw_bf = (unsigned short*)(ws);             // 384KB
  unsigned short* pw_bf   = (unsigned short*)(ws + 0x60000);   // 128KB
  unsigned short* wvt_bf  = (unsigned short*)(ws + 0x80000);   // 128KB
  float* avec  = (float*)(ws + 0xA0000);
  float* evec  = (float*)(ws + 0xA2000);
  float* wsv   = (float*)(ws + 0xA6000);
  float* hvec  = (float*)(ws + 0xAA000);
  float* abv   = (float*)(ws + 0xAC000);
  float* sxpart = (float*)(ws + 1 * MB);                   // 512KB
  float* part   = (float*)(ws + 2 * MB);                   // 16MB
  unsigned short* Gbf = (unsigned short*)(ws + 18 * MB);   // 1MB
  unsigned short* Ubf = (unsigned short*)(ws + 19 * MB);   // 2MB
  unsigned short* Abf = (unsigned short*)(ws + 21 * MB);   // 1MB
  unsigned short* Y1  = (unsigned short*)(ws + 22 * MB);   // 1MB
  unsigned short* Fbf = (unsigned short*)(ws + 23 * MB);   // 1MB
  unsigned short* xbf = (unsigned short*)(ws + 24 * MB);   // 16MB
  unsigned short* xT  = (unsigned short*)(ws + 40 * MB);   // 16MB
  if (ws_size < 56 * MB) return;

  // 1. x prep + weight conversions
  prep_k<<<2320, 256, 0, stream>>>(x, qkv_w, proj_w, xbf, xT, sxpart,
                                   qkvw_bf, pw_bf, wvt_bf);

  // 2. Sxx = X X^T (64^2 tiles, split-K 8 -> 1024 blocks, 4/CU)
  sxx64_k<<<dim3(4, 4, 64), 256, 0, stream>>>(xbf, part);

  // 3. gfill2: stats + G + wsv (one kernel)
  gfill2_k<<<dim3(16, 8), 256, 0, stream>>>(part, sxpart, gamma, beta, qkvw_bf,
                                            avec, evec, wsv, Gbf);

  // 4. U = [Wq;Wk] @ G
  ugemm_k<<<dim3(4, 8, 8), 256, 0, stream>>>(qkvw_bf, Gbf, Ubf);

  // 5. logits + inline norms + softmax + A.bv
  logsm_k<<<dim3(4, 8), 256, 0, stream>>>(Ubf, qkvw_bf, wsv, qkv_b, temp, Abf, abv);

  // 6. Y1 = Wv^T A^T (+ hvec base on y==0)
  y1h_k<<<dim3(4, 4, 8), 256, 0, stream>>>(wvt_bf, Abf, abv, proj_w, proj_b, Y1, hvec);

  // 7. F + Fbf(=F diag(a)+I) + hvec += F e
  fgen_k<<<dim3(4, 4, 8), 256, 0, stream>>>(pw_bf, Y1, avec, evec, Fbf, hvec);

  // 8. out = F~ @ X + h~ (2048 blocks, 8/CU)
  out64_k<<<dim3(64, 4, 8), 256, 0, stream>>>(Fbf, xT, hvec, out);
}